// Round 6
// baseline (1664.397 us; speedup 1.0000x reference)
//
#include <hip/hip_runtime.h>
#include <math.h>

#define BB 8
#define NN 1024
#define DD 128
#define HH 2
#define LL 4
#define DFCN 512

typedef __attribute__((ext_vector_type(8))) short bf16x8;
typedef __attribute__((ext_vector_type(8))) _Float16 f16x8;
typedef __attribute__((ext_vector_type(4))) float f32x4;
typedef unsigned long long u64;
typedef unsigned short ushortT;

// fp32 -> bf16 (RNE) and back
static __device__ __forceinline__ unsigned short f2bf(float f) {
    unsigned u = __float_as_uint(f);
    u += 0x7FFF + ((u >> 16) & 1);
    return (unsigned short)(u >> 16);
}
static __device__ __forceinline__ float bf2f(unsigned short s) {
    return __uint_as_float(((unsigned)s) << 16);
}
// fp32 <-> fp16
static __device__ __forceinline__ unsigned short f2h(float f) {
    _Float16 h = (_Float16)f; return *(unsigned short*)&h;
}
static __device__ __forceinline__ float h2f(unsigned short u) {
    _Float16 h; *(unsigned short*)&h = u; return (float)h;
}

// ---------------------------------------------------------------------------
// Generic small-K GEMM (fp32 VALU): Y[M,NOUT] = X[M,K] @ W[K,NOUT]
// MODE 0: plain row-major fp32 out
// MODE 1: scatter out [B,N,H*D] -> [B,H,N,D] fp32 + bf16 hi/lo split outs
// MODE 2: gather input [B,H,N,D] -> [B,N,H*D] with relu on load
// MODE 3: row-major out as bf16 hi/lo split only (no fp32)
// ---------------------------------------------------------------------------
template<int K, int NOUT, int TM, bool RELU_OUT, int MODE>
__global__ __launch_bounds__(256) void k_gemm(const float* __restrict__ X,
                                              const float* __restrict__ W,
                                              float* __restrict__ Y,
                                              ushortT* __restrict__ O1,
                                              ushortT* __restrict__ O2) {
    constexpr int KC  = 32;
    constexpr int CT  = NOUT / 4;
    constexpr int RT  = 256 / CT;
    constexpr int RPT = TM / RT;
    __shared__ float Xs[TM][KC];
    __shared__ float Ws[KC][NOUT];
    const int t   = threadIdx.x;
    const int ct  = t % CT, rt = t / CT;
    const int row0 = blockIdx.x * TM;
    float acc[RPT][4];
#pragma unroll
    for (int r = 0; r < RPT; r++) { acc[r][0]=acc[r][1]=acc[r][2]=acc[r][3]=0.f; }

    for (int k0 = 0; k0 < K; k0 += KC) {
        constexpr int NX4 = TM * KC / 4;
#pragma unroll
        for (int p = 0; p < NX4 / 256; p++) {
            int idx = t + p * 256;
            int r = idx / (KC / 4), kg = idx % (KC / 4);
            int m = row0 + r;
            float4 v;
            if (MODE == 2) {
                int b = m / NN, n = m % NN;
                int hh = k0 / DD;
                int d  = (k0 % DD) + kg * 4;
                v = *(const float4*)&X[(((size_t)b * HH + hh) * NN + n) * DD + d];
                v.x = fmaxf(v.x, 0.f); v.y = fmaxf(v.y, 0.f);
                v.z = fmaxf(v.z, 0.f); v.w = fmaxf(v.w, 0.f);
            } else {
                v = *(const float4*)&X[(size_t)m * K + k0 + kg * 4];
            }
            *(float4*)&Xs[r][kg * 4] = v;
        }
        constexpr int NW4 = KC * NOUT / 4;
#pragma unroll
        for (int p = 0; p < NW4 / 256; p++) {
            int idx = t + p * 256;
            int kk = idx / (NOUT / 4), cg = idx % (NOUT / 4);
            *(float4*)&Ws[kk][cg * 4] =
                *(const float4*)&W[(size_t)(k0 + kk) * NOUT + cg * 4];
        }
        __syncthreads();
#pragma unroll
        for (int kk = 0; kk < KC; kk++) {
            float4 wv = *(const float4*)&Ws[kk][ct * 4];
#pragma unroll
            for (int r = 0; r < RPT; r++) {
                float xv = Xs[rt * RPT + r][kk];
                acc[r][0] += xv * wv.x; acc[r][1] += xv * wv.y;
                acc[r][2] += xv * wv.z; acc[r][3] += xv * wv.w;
            }
        }
        __syncthreads();
    }
#pragma unroll
    for (int r = 0; r < RPT; r++) {
        int m = row0 + rt * RPT + r;
        float4 v = make_float4(acc[r][0], acc[r][1], acc[r][2], acc[r][3]);
        if (RELU_OUT) {
            v.x = fmaxf(v.x, 0.f); v.y = fmaxf(v.y, 0.f);
            v.z = fmaxf(v.z, 0.f); v.w = fmaxf(v.w, 0.f);
        }
        if (MODE == 1) {
            int b = m / NN, n = m % NN;
            int o = ct * 4; int hh = o / DD, d = o % DD;
            size_t addr = (((size_t)b * HH + hh) * NN + n) * DD + d;
            *(float4*)&Y[addr] = v;
            ushort4 hi, lo;
            hi.x = f2bf(v.x); lo.x = f2bf(v.x - bf2f(hi.x));
            hi.y = f2bf(v.y); lo.y = f2bf(v.y - bf2f(hi.y));
            hi.z = f2bf(v.z); lo.z = f2bf(v.z - bf2f(hi.z));
            hi.w = f2bf(v.w); lo.w = f2bf(v.w - bf2f(hi.w));
            *(ushort4*)&O1[addr] = hi;
            *(ushort4*)&O2[addr] = lo;
        } else if (MODE == 3) {
            size_t addr = (size_t)m * NOUT + ct * 4;
            ushort4 hi, lo;
            hi.x = f2bf(v.x); lo.x = f2bf(v.x - bf2f(hi.x));
            hi.y = f2bf(v.y); lo.y = f2bf(v.y - bf2f(hi.y));
            hi.z = f2bf(v.z); lo.z = f2bf(v.z - bf2f(hi.z));
            hi.w = f2bf(v.w); lo.w = f2bf(v.w - bf2f(hi.w));
            *(ushort4*)&O1[addr] = hi;
            *(ushort4*)&O2[addr] = lo;
        } else {
            *(float4*)&Y[(size_t)m * NOUT + ct * 4] = v;
        }
    }
}

// ---------------------------------------------------------------------------
// e[j,k] = hW_j.h_k + h_j.hW_k via split-bf16 MFMA (6 terms, lo*lo dropped).
// SYMMETRIC: only upper-triangle 64x64 tiles (tj<=tk), off-diag written twice
// (normal strided + transposed float4 -- contiguous since C/D q walks rows).
// 136 tiles/bh, LDS 40KB -> 4 blocks/CU.
// ---------------------------------------------------------------------------
__global__ __launch_bounds__(256) void k_esym_mfma(const ushortT* __restrict__ wHi,
                                                   const ushortT* __restrict__ wLo,
                                                   const ushortT* __restrict__ hHi,
                                                   const ushortT* __restrict__ hLo,
                                                   float* __restrict__ e) {
    __shared__ ushortT sWjHi[64*40], sWjLo[64*40], sHjHi[64*40], sHjLo[64*40];
    __shared__ ushortT sWkHi[64*40], sWkLo[64*40], sHkHi[64*40], sHkLo[64*40];
    const int bh = blockIdx.z;
    int idx = blockIdx.x, tj = 0;                 // tri index -> (tj,tk), tj<=tk
    while (idx >= 16 - tj) { idx -= 16 - tj; tj++; }
    const int tk = tj + idx;
    const int j0 = tj * 64, k0 = tk * 64;
    const int t = threadIdx.x;
    const int wave = t >> 6, lane = t & 63;
    const int wr = wave >> 1, wc = wave & 1;
    const int lrow = lane & 15, lg = lane >> 4;

    f32x4 acc[2][2];
#pragma unroll
    for (int m = 0; m < 2; m++)
#pragma unroll
        for (int n = 0; n < 2; n++) {
            acc[m][n][0] = 0.f; acc[m][n][1] = 0.f;
            acc[m][n][2] = 0.f; acc[m][n][3] = 0.f;
        }

    const size_t bhbase = (size_t)bh * NN * DD;

    for (int d0 = 0; d0 < DD; d0 += 32) {
        __syncthreads();
        // stage one [64][32] bf16 tile per (matrix, side): 1x 16B per thread
        {
            const int row = t >> 2, cu = (t & 3) * 8;
#define STAGE1(SRC, DST, BASE)                                                    \
            *(uint4*)&DST[row * 40 + cu] =                                        \
                *(const uint4*)&SRC[bhbase + (size_t)(BASE + row) * DD + d0 + cu];
            STAGE1(wHi, sWjHi, j0) STAGE1(wLo, sWjLo, j0)
            STAGE1(hHi, sHjHi, j0) STAGE1(hLo, sHjLo, j0)
            STAGE1(wHi, sWkHi, k0) STAGE1(wLo, sWkLo, k0)
            STAGE1(hHi, sHkHi, k0) STAGE1(hLo, sHkLo, k0)
#undef STAGE1
        }
        __syncthreads();

        bf16x8 a0[2], a1[2], b0[2], b1[2];
        // ---- group 1: A = hW_j, B = h_k ----
#pragma unroll
        for (int m = 0; m < 2; m++) {
            const int off = (wr * 32 + m * 16 + lrow) * 40 + lg * 8;
            a0[m] = *(const bf16x8*)&sWjHi[off];
            a1[m] = *(const bf16x8*)&sWjLo[off];
        }
#pragma unroll
        for (int n = 0; n < 2; n++) {
            const int off = (wc * 32 + n * 16 + lrow) * 40 + lg * 8;
            b0[n] = *(const bf16x8*)&sHkHi[off];
            b1[n] = *(const bf16x8*)&sHkLo[off];
        }
#pragma unroll
        for (int m = 0; m < 2; m++)
#pragma unroll
            for (int n = 0; n < 2; n++) {
                acc[m][n] = __builtin_amdgcn_mfma_f32_16x16x32_bf16(a0[m], b0[n], acc[m][n], 0, 0, 0);
                acc[m][n] = __builtin_amdgcn_mfma_f32_16x16x32_bf16(a0[m], b1[n], acc[m][n], 0, 0, 0);
                acc[m][n] = __builtin_amdgcn_mfma_f32_16x16x32_bf16(a1[m], b0[n], acc[m][n], 0, 0, 0);
            }
        // ---- group 2: A = h_j, B = hW_k ----
#pragma unroll
        for (int m = 0; m < 2; m++) {
            const int off = (wr * 32 + m * 16 + lrow) * 40 + lg * 8;
            a0[m] = *(const bf16x8*)&sHjHi[off];
            a1[m] = *(const bf16x8*)&sHjLo[off];
        }
#pragma unroll
        for (int n = 0; n < 2; n++) {
            const int off = (wc * 32 + n * 16 + lrow) * 40 + lg * 8;
            b0[n] = *(const bf16x8*)&sWkHi[off];
            b1[n] = *(const bf16x8*)&sWkLo[off];
        }
#pragma unroll
        for (int m = 0; m < 2; m++)
#pragma unroll
            for (int n = 0; n < 2; n++) {
                acc[m][n] = __builtin_amdgcn_mfma_f32_16x16x32_bf16(a0[m], b0[n], acc[m][n], 0, 0, 0);
                acc[m][n] = __builtin_amdgcn_mfma_f32_16x16x32_bf16(a0[m], b1[n], acc[m][n], 0, 0, 0);
                acc[m][n] = __builtin_amdgcn_mfma_f32_16x16x32_bf16(a1[m], b0[n], acc[m][n], 0, 0, 0);
            }
    }

    // C/D layout: col = lane&15, row = (lane>>4)*4 + q
#pragma unroll
    for (int m = 0; m < 2; m++)
#pragma unroll
        for (int n = 0; n < 2; n++) {
            const int r = j0 + wr * 32 + m * 16 + lg * 4;
            const int cc = k0 + wc * 32 + n * 16 + lrow;
            float* dst = &e[((size_t)bh * NN + r) * NN + cc];
#pragma unroll
            for (int q = 0; q < 4; q++) dst[(size_t)q * NN] = acc[m][n][q];
            if (tj != tk) {  // mirror tile: e[cc][r..r+3] contiguous float4
                *(float4*)&e[((size_t)bh * NN + cc) * NN + r] =
                    make_float4(acc[m][n][0], acc[m][n][1], acc[m][n][2], acc[m][n][3]);
            }
        }
}

// ---------------------------------------------------------------------------
// Column nnz bitmask build (atomic-free). bits[b][k][t] bit jj <=> adj[b][64t+jj][k]!=0
// ---------------------------------------------------------------------------
__global__ __launch_bounds__(256) void k_buildT(const float* __restrict__ adj,
                                                u64* __restrict__ bits) {
    const int gid = blockIdx.x * 256 + threadIdx.x;   // 8*16*1024
    const int k  = gid & 1023;
    const int tw = (gid >> 10) & 15;
    const int b  = gid >> 14;
    const float* ac = adj + ((size_t)b << 20) + k;
    u64 w = 0;
#pragma unroll 8
    for (int jj = 0; jj < 64; jj++) {
        if (ac[(size_t)(tw * 64 + jj) << 10] != 0.f) w |= 1ull << jj;
    }
    bits[((size_t)((b << 10) | k)) * 16 + tw] = w;
}

// per-column popcount (layer-independent, once per branch)
__global__ __launch_bounds__(256) void k_cnt(const u64* __restrict__ bits,
                                             int* __restrict__ ccnt) {
    const int gid = blockIdx.x * 256 + threadIdx.x;   // 8192
    const u64* wb = bits + (size_t)gid * 16;
    int c = 0;
#pragma unroll
    for (int tw = 0; tw < 16; tw++) c += __popcll(wb[tw]);
    ccnt[gid] = c;
}

// ---------------------------------------------------------------------------
// Softmax pass A: partial online max/sum per (bh, 4-col group, 16-row chunk).
// ---------------------------------------------------------------------------
__global__ __launch_bounds__(256) void k_smA(const float* __restrict__ e,
                                             const u64* __restrict__ bits,
                                             float* __restrict__ pm,
                                             float* __restrict__ ps) {
    const int gid = blockIdx.x * 256 + threadIdx.x;   // 16*64*256
    const int kg = gid & 255;                          // 4-col group
    const int jc = (gid >> 8) & 63;                    // 16-row chunk
    const int bh = gid >> 14;
    const int b  = bh >> 1;
    const int k4 = kg * 4;
    const int tw = jc >> 2;                            // u64 word index
    const int bo = (jc & 3) * 16;                      // bit offset in word
    u64 w[4];
#pragma unroll
    for (int i = 0; i < 4; i++)
        w[i] = bits[((size_t)((b << 10) | (k4 + i))) * 16 + tw];
    const float* ec = e + ((size_t)bh << 20) + (size_t)(jc * 16) * NN + k4;
    float m[4] = {0.f, 0.f, 0.f, 0.f};
    float s[4] = {0.f, 0.f, 0.f, 0.f};
#pragma unroll
    for (int r = 0; r < 16; r++) {
        const float4 ev = *(const float4*)&ec[(size_t)r * NN];
        const float evs[4] = {ev.x, ev.y, ev.z, ev.w};
#pragma unroll
        for (int i = 0; i < 4; i++) {
            const bool on = (w[i] >> (bo + r)) & 1;
            const float v = on ? evs[i] : 0.f;
            const float mn = fmaxf(m[i], v);
            s[i] = s[i] * __expf(m[i] - mn) + (on ? __expf(v - mn) : 0.f);
            m[i] = mn;
        }
    }
    const size_t o = (((size_t)bh * 64 + jc) << 10) + k4;
    *(float4*)&pm[o] = make_float4(m[0], m[1], m[2], m[3]);
    *(float4*)&ps[o] = make_float4(s[0], s[1], s[2], s[3]);
}

// Softmax pass B: wave-parallel combine of 64 partials per column.
// 4 waves each fold 16 partials, LDS-combine; denom += (1024-cnt)exp(-M).
__global__ __launch_bounds__(256) void k_smB(const float* __restrict__ pm,
                                             const float* __restrict__ ps,
                                             const int* __restrict__ ccnt,
                                             float* __restrict__ smax,
                                             float* __restrict__ sdinv) {
    __shared__ float lm[4][64], ls[4][64];
    const int t = threadIdx.x, q = t >> 6, lane = t & 63;
    const int colg = blockIdx.x * 64 + lane;          // grid 256 -> 16384 cols
    const int bh = colg >> 10, k = colg & 1023;
    const int b  = bh >> 1;
    float M = 0.f, S = 0.f;
#pragma unroll 4
    for (int i = 0; i < 16; i++) {
        const int jc = q * 16 + i;
        const size_t o = (((size_t)bh * 64 + jc) << 10) + k;
        const float pmv = pm[o], psv = ps[o];
        const float mn = fmaxf(M, pmv);
        S = S * __expf(M - mn) + psv * __expf(pmv - mn);
        M = mn;
    }
    lm[q][lane] = M; ls[q][lane] = S;
    __syncthreads();
    if (q == 0) {
#pragma unroll
        for (int qq = 1; qq < 4; qq++) {
            const float pmv = lm[qq][lane], psv = ls[qq][lane];
            const float mn = fmaxf(M, pmv);
            S = S * __expf(M - mn) + psv * __expf(pmv - mn);
            M = mn;
        }
        S += (float)(NN - ccnt[(b << 10) + k]) * __expf(-M);
        smax[colg] = M;
        sdinv[colg] = 1.f / S;
    }
}

// Softmax pass C: dense f16 att write (zeros where masked).
__global__ __launch_bounds__(256) void k_smC(const float* __restrict__ e,
                                             const u64* __restrict__ bits,
                                             const float* __restrict__ smax,
                                             const float* __restrict__ sdinv,
                                             ushortT* __restrict__ att) {
    const int gid = blockIdx.x * 256 + threadIdx.x;   // 16*64*256
    const int kg = gid & 255;
    const int jc = (gid >> 8) & 63;
    const int bh = gid >> 14;
    const int b  = bh >> 1;
    const int k4 = kg * 4;
    const int tw = jc >> 2;
    const int bo = (jc & 3) * 16;
    u64 w[4];
#pragma unroll
    for (int i = 0; i < 4; i++)
        w[i] = bits[((size_t)((b << 10) | (k4 + i))) * 16 + tw];
    const float4 m4 = *(const float4*)&smax[(bh << 10) + k4];
    const float4 d4 = *(const float4*)&sdinv[(bh << 10) + k4];
    const float ms[4] = {m4.x, m4.y, m4.z, m4.w};
    const float ds[4] = {d4.x, d4.y, d4.z, d4.w};
    const float* ec = e + ((size_t)bh << 20) + (size_t)(jc * 16) * NN + k4;
    ushortT* ac = att + ((size_t)bh << 20) + (size_t)(jc * 16) * NN + k4;
#pragma unroll
    for (int r = 0; r < 16; r++) {
        const float4 ev = *(const float4*)&ec[(size_t)r * NN];
        const float evs[4] = {ev.x, ev.y, ev.z, ev.w};
        ushort4 o;
        ushortT os[4];
#pragma unroll
        for (int i = 0; i < 4; i++) {
            const bool on = (w[i] >> (bo + r)) & 1;
            os[i] = f2h(on ? __expf(evs[i] - ms[i]) * ds[i] : 0.f);
        }
        o.x = os[0]; o.y = os[1]; o.z = os[2]; o.w = os[3];
        *(ushort4*)&ac[(size_t)r * NN] = o;
    }
}

// ---------------------------------------------------------------------------
// Transpose h fp32 [bh][n][d] -> hT f16 [bh][d][n]
// ---------------------------------------------------------------------------
__global__ __launch_bounds__(256) void k_trT(const float* __restrict__ h,
                                             ushortT* __restrict__ hT) {
    __shared__ float tile[64][65];
    const int bh = blockIdx.z;
    const int n0 = blockIdx.x * 64, d0 = blockIdx.y * 64;
    const int t = threadIdx.x;
#pragma unroll
    for (int q = 0; q < 16; q++) {
        const int idx = t + q * 256;
        const int row = idx >> 6, col = idx & 63;
        tile[row][col] = h[(size_t)bh * 131072 + (size_t)(n0 + row) * DD + d0 + col];
    }
    __syncthreads();
#pragma unroll
    for (int q = 0; q < 16; q++) {
        const int idx = t + q * 256;
        const int row = idx >> 6, col = idx & 63;
        hT[(size_t)bh * 131072 + (size_t)(d0 + row) * NN + n0 + col] = f2h(tile[col][row]);
    }
}

// Transpose zT f16 [bh][d][n] -> zfin fp32 [bh][n][d]
__global__ __launch_bounds__(256) void k_fin(const ushortT* __restrict__ zT,
                                             float* __restrict__ zfin) {
    __shared__ float tile[64][65];
    const int bh = blockIdx.z;
    const int n0 = blockIdx.x * 64, d0 = blockIdx.y * 64;
    const int t = threadIdx.x;
#pragma unroll
    for (int q = 0; q < 16; q++) {
        const int idx = t + q * 256;
        const int row = idx >> 6, col = idx & 63;
        tile[row][col] = h2f(zT[(size_t)bh * 131072 + (size_t)(d0 + row) * NN + n0 + col]);
    }
    __syncthreads();
#pragma unroll
    for (int q = 0; q < 16; q++) {
        const int idx = t + q * 256;
        const int row = idx >> 6, col = idx & 63;
        zfin[(size_t)bh * 131072 + (size_t)(n0 + row) * DD + d0 + col] = tile[col][row];
    }
}

// ---------------------------------------------------------------------------
// Dense f16 MFMA hop: out = relu(att @ zin^T-layout), optional fused beta-mix,
// transposed output write. 32-row i-tiles, grid 32x16 = 512 blocks, LDS 23KB.
// ---------------------------------------------------------------------------
template<bool FUSED>
__global__ __launch_bounds__(256) void k_hop(const ushortT* __restrict__ att,
                                             const ushortT* __restrict__ zin,
                                             const ushortT* __restrict__ hT,
                                             const float* __restrict__ beta,
                                             ushortT* __restrict__ zout) {
    __shared__ ushortT sA[32 * 72];
    __shared__ ushortT sB[128 * 72];
    const int bh = blockIdx.y;
    const int i0 = blockIdx.x * 32;
    const int t = threadIdx.x, wave = t >> 6, lane = t & 63;
    const int wr = wave >> 1, wc = wave & 1;
    const int lrow = lane & 15, lg = lane >> 4;
    const ushortT* attb = att + ((size_t)bh << 20);
    const ushortT* zb   = zin + (size_t)bh * 131072;

    f32x4 acc[4];
#pragma unroll
    for (int n = 0; n < 4; n++) {
        acc[n][0]=0.f; acc[n][1]=0.f; acc[n][2]=0.f; acc[n][3]=0.f;
    }

    for (int j0 = 0; j0 < NN; j0 += 64) {
        __syncthreads();
        {   // stage att 32 rows x 64 cols: one uint4 per thread
            const int row = t >> 3, c8 = (t & 7) * 8;
            *(uint4*)&sA[row * 72 + c8] =
                *(const uint4*)&attb[(size_t)(i0 + row) * NN + j0 + c8];
        }
#pragma unroll
        for (int q = 0; q < 4; q++) {
            const int u = t + q * 256;
            const int row = u >> 3, c8 = (u & 7) * 8;
            *(uint4*)&sB[row * 72 + c8] =
                *(const uint4*)&zb[(size_t)row * NN + j0 + c8];
        }
        __syncthreads();
#pragma unroll
        for (int ks = 0; ks < 2; ks++) {
            f16x8 a, b[4];
            a = *(const f16x8*)&sA[(wr * 16 + lrow) * 72 + ks * 32 + lg * 8];
#pragma unroll
            for (int n = 0; n < 4; n++)
                b[n] = *(const f16x8*)&sB[(wc * 64 + n * 16 + lrow) * 72 + ks * 32 + lg * 8];
#pragma unroll
            for (int n = 0; n < 4; n++)
                acc[n] = __builtin_amdgcn_mfma_f32_16x16x32_f16(a, b[n], acc[n], 0, 0, 0);
        }
    }

    const float* betab = beta + ((size_t)bh << 10);
    const ushortT* hTb = hT + (size_t)bh * 131072;
    ushortT* zo = zout + (size_t)bh * 131072;
#pragma unroll
    for (int n = 0; n < 4; n++) {
        const int d = wc * 64 + n * 16 + lrow;
        const int i = i0 + wr * 16 + lg * 4;
        ushort4 o;
        float vq[4];
        if (FUSED) {
            const float4 bev = *(const float4*)&betab[i];
            const ushort4 hv = *(const ushort4*)&hTb[(size_t)d * NN + i];
            vq[0] = bev.x * h2f(hv.x) + (1.f - bev.x) * fmaxf(acc[n][0], 0.f);
            vq[1] = bev.y * h2f(hv.y) + (1.f - bev.y) * fmaxf(acc[n][1], 0.f);
            vq[2] = bev.z * h2f(hv.z) + (1.f - bev.z) * fmaxf(acc[n][2], 0.f);
            vq[3] = bev.w * h2f(hv.w) + (1.f - bev.w) * fmaxf(acc[n][3], 0.f);
        } else {
            vq[0] = fmaxf(acc[n][0], 0.f); vq[1] = fmaxf(acc[n][1], 0.f);
            vq[2] = fmaxf(acc[n][2], 0.f); vq[3] = fmaxf(acc[n][3], 0.f);
        }
        o.x = f2h(vq[0]); o.y = f2h(vq[1]); o.z = f2h(vq[2]); o.w = f2h(vq[3]);
        *(ushort4*)&zo[(size_t)d * NN + i] = o;
    }
}

// beta partials: thread per (dchunk of 32, bh, n); pb[dc][bh][n]
__global__ __launch_bounds__(256) void k_betaA(const ushortT* __restrict__ hT,
                                               const ushortT* __restrict__ azT,
                                               const float* __restrict__ Wbw,
                                               float* __restrict__ pb) {
    const int gid = blockIdx.x * 256 + threadIdx.x;   // 65536
    const int n  = gid & 1023;
    const int bh = (gid >> 10) & 15;
    const int dc = gid >> 14;                         // 0..3
    const size_t base = (size_t)bh * 131072 + ((size_t)(dc * 32) << 10) + n;
    const ushortT* hp = hT  + base;
    const ushortT* ap = azT + base;
    float s = 0.f;
#pragma unroll 8
    for (int d = 0; d < 32; d++)
        s += h2f(hp[(size_t)d << 10]) * Wbw[dc * 32 + d]
           + h2f(ap[(size_t)d << 10]) * Wbw[DD + dc * 32 + d];
    pb[gid] = s;
}

__global__ __launch_bounds__(256) void k_betaB(const float* __restrict__ pb,
                                               const float* __restrict__ Wbb,
                                               float* __restrict__ beta) {
    const int gid = blockIdx.x * 256 + threadIdx.x;   // 16384
    const float s = pb[gid] + pb[gid + 16384] + pb[gid + 32768] + pb[gid + 49152];
    beta[gid] = 1.f / (1.f + expf(-(s + Wbb[0])));
}

// zT = beta*hT + (1-beta)*azT (f16 transposed, 8 elems/thread)
__global__ __launch_bounds__(256) void k_zupT(const ushortT* __restrict__ hT,
                                              const ushortT* __restrict__ azT,
                                              const float* __restrict__ beta,
                                              ushortT* __restrict__ zT) {
    const int gid = blockIdx.x * 256 + threadIdx.x;   // 2097152/8
    const size_t base = (size_t)gid * 8;
    const int n0 = (int)(base & 1023);
    const int bh = (int)(base >> 17);
    ushortT hu[8], au[8], ou[8];
    *(uint4*)hu = *(const uint4*)&hT[base];
    *(uint4*)au = *(const uint4*)&azT[base];
    const float4 b0 = *(const float4*)&beta[(bh << 10) + n0];
    const float4 b1 = *(const float4*)&beta[(bh << 10) + n0 + 4];
    const float be[8] = {b0.x, b0.y, b0.z, b0.w, b1.x, b1.y, b1.z, b1.w};
#pragma unroll
    for (int i = 0; i < 8; i++)
        ou[i] = f2h(be[i] * h2f(hu[i]) + (1.f - be[i]) * h2f(au[i]));
    *(uint4*)&zT[base] = *(uint4*)ou;
}

__global__ __launch_bounds__(256) void k_sub(const float* __restrict__ c2,
                                             const float* __restrict__ c1,
                                             float* __restrict__ c) {
    const int g = blockIdx.x * 256 + threadIdx.x;
    const float4 a = ((const float4*)c2)[g];
    const float4 b = ((const float4*)c1)[g];
    ((float4*)c)[g] = make_float4(a.x - b.x, a.y - b.y, a.z - b.z, a.w - b.w);
}

__global__ void k_pool(const float* __restrict__ c, const float* __restrict__ valid,
                       float* __restrict__ pooled) {
    const int b = blockIdx.x, d = threadIdx.x;     // 128 threads
    const float* cb = c + (size_t)b * NN * DD;
    const float* vb = valid + (size_t)b * NN;
    float s = 0.f, sv = 0.f;
    for (int n = 0; n < NN; n++) { float v = vb[n]; s += cb[(size_t)n * DD + d] * v; sv += v; }
    pooled[b * DD + d] = s / sv;
}

template<int K, int NOUT, bool RELU>
__global__ void k_fc(const float* __restrict__ X, const float* __restrict__ W,
                     const float* __restrict__ bias, float* __restrict__ Y) {
    const int gid = blockIdx.x * blockDim.x + threadIdx.x;
    if (gid >= BB * NOUT) return;
    const int b = gid / NOUT, o = gid % NOUT;
    float s = bias[o];
    for (int i = 0; i < K; i++) s += X[(size_t)b * K + i] * W[(size_t)i * NOUT + o];
    Y[gid] = RELU ? fmaxf(s, 0.f) : s;
}

__global__ void k_fc2(const float* __restrict__ X, const float* __restrict__ W,
                      const float* __restrict__ bias, float* __restrict__ out) {
    const int b = threadIdx.x >> 6, lane = threadIdx.x & 63;
    float s = 0.f;
    for (int i = lane; i < DFCN; i += 64) s += X[(size_t)b * DFCN + i] * W[i];
#pragma unroll
    for (int off = 32; off > 0; off >>= 1) s += __shfl_down(s, off);
    if (lane == 0) out[b] = 1.f / (1.f + expf(-(s + bias[0])));
}

// ---------------------------------------------------------------------------
extern "C" void kernel_launch(void* const* d_in, const int* in_sizes, int n_in,
                              void* d_out, int out_size, void* d_ws, size_t ws_size,
                              hipStream_t stream) {
    const float* x        = (const float*)d_in[0];
    const float* adj1     = (const float*)d_in[1];
    const float* adj2     = (const float*)d_in[2];
    const float* valid    = (const float*)d_in[3];
    const float* embede_w = (const float*)d_in[4];
    const float* Wh       = (const float*)d_in[5];
    const float* We       = (const float*)d_in[6];
    const float* Wbw      = (const float*)d_in[7];
    const float* Wbb      = (const float*)d_in[8];
    const float* Wo       = (const float*)d_in[9];
    const float* fc0_w    = (const float*)d_in[10];
    const float* fc0_b    = (const float*)d_in[11];
    const float* fc1_w    = (const float*)d_in[12];
    const float* fc1_b    = (const float*)d_in[13];
    const float* fc2_w    = (const float*)d_in[14];
    const float* fc2_b    = (const float*)d_in[15];

    // ---- workspace carve: ~169 MB ----
    float* ws = (float*)d_ws;
    float* c      = ws;                          // 1,048,576 f
    float* h      = c      + (size_t)1048576;    // 2,097,152 f
    float* e      = h      + (size_t)2097152;    // 16,777,216 f
    float* c1     = e      + (size_t)16777216;   // 1,048,576 f
    float* c2     = c1     + (size_t)1048576;    // 1,048,576 f
    float* zfin   = c2     + (size_t)1048576;    // 2,097,152 f
    float* beta   = zfin   + (size_t)2097152;    // 16,384 f
    float* pm     = beta   + (size_t)16384;      // 1,048,576 f ([bh][64][1024])
    float* ps     = pm     + (size_t)1048576;    // 1,048,576 f
    float* smax   = ps     + (size_t)1048576;    // 16,384 f
    float* sdinv  = smax   + (size_t)16384;      // 16,384 f
    float* pb     = sdinv  + (size_t)16384;      // 65,536 f
    float* pooled = pb     + (size_t)65536;      // 1,024 f
    float* f0     = pooled + (size_t)1024;       // 4,096 f
    float* f1     = f0     + (size_t)4096;       // 4,096 f
    ushortT* hHi  = (ushortT*)(f1 + 4096);       // 2,097,152 us each
    ushortT* hLo  = hHi + (size_t)2097152;
    ushortT* wHi  = hLo + (size_t)2097152;
    ushortT* wLo  = wHi + (size_t)2097152;
    ushortT* hT   = wLo + (size_t)2097152;
    ushortT* zTa  = hT  + (size_t)2097152;
    ushortT* zTb  = zTa + (size_t)2097152;       // also serves as azT
    ushortT* att  = zTb + (size_t)2097152;       // 16,777,216 us
    u64* bits1    = (u64*)(att + (size_t)16777216); // 131,072 u64
    u64* bits2    = bits1 + (size_t)131072;
    int* ccnt1    = (int*)(bits2 + (size_t)131072); // 8,192 i
    int* ccnt2    = ccnt1 + 8192;

    // column nnz bitmasks + counts (atomic-free, layer-independent)
    k_buildT<<<512, 256, 0, stream>>>(adj1, bits1);
    k_buildT<<<512, 256, 0, stream>>>(adj2, bits2);
    k_cnt<<<32, 256, 0, stream>>>(bits1, ccnt1);
    k_cnt<<<32, 256, 0, stream>>>(bits2, ccnt2);

    // c = x @ embede_w
    k_gemm<128,128,64,false,0><<<128, 256, 0, stream>>>(x, embede_w, c, nullptr, nullptr);

    for (int k = 0; k < LL; k++) {
        const int nhop = k + 1;
        // h = relu(c @ Wh[k]) -> [B,H,N,D] fp32 + bf16 hi/lo split
        k_gemm<128,256,32,true,1><<<256, 256, 0, stream>>>(c, Wh + (size_t)k*32768, h, hHi, hLo);
        // hW = h @ We[k] -> bf16 hi/lo split directly
        k_gemm<128,128,64,false,3><<<256, 256, 0, stream>>>(h, We + (size_t)k*16384, nullptr, wHi, wLo);
        // hT f16 [bh][d][n]
        k_trT<<<dim3(16,2,16), 256, 0, stream>>>(h, hT);
        // dense symmetric e: upper-tri 64x64 tiles, dual write
        k_esym_mfma<<<dim3(136,1,16), 256, 0, stream>>>(wHi, wLo, hHi, hLo, e);

        for (int br = 0; br < 2; br++) {
            const u64* bits = (br == 0) ? bits1 : bits2;
            const int* ccnt = (br == 0) ? ccnt1 : ccnt2;
            float*     cb   = (br == 0) ? c1    : c2;

            // masked column-softmax -> dense f16 att
            k_smA<<<1024, 256, 0, stream>>>(e, bits, pm, ps);
            k_smB<<<256, 256, 0, stream>>>(pm, ps, ccnt, smax, sdinv);
            k_smC<<<1024, 256, 0, stream>>>(e, bits, smax, sdinv, att);

            // hop 0: azT = relu(att@h)
            k_hop<false><<<dim3(32,16), 256, 0, stream>>>(att, hT, hT, beta, zTb);
            k_betaA<<<256, 256, 0, stream>>>(hT, zTb, Wbw + (size_t)k*256, pb);
            k_betaB<<<64, 256, 0, stream>>>(pb, Wbb + k, beta);
            k_zupT<<<1024, 256, 0, stream>>>(hT, zTb, beta, zTa);
            // hops 1..nhop-1, fused beta-mix
            ushortT* zA = zTa; ushortT* zB = zTb;
            for (int tpp = 1; tpp < nhop; tpp++) {
                k_hop<true><<<dim3(32,16), 256, 0, stream>>>(att, zA, hT, beta, zB);
                ushortT* tmp = zA; zA = zB; zB = tmp;
            }
            // zfin fp32 [bh][n][d]; cb = relu(zfin gathered) @ Wo[k]
            k_fin<<<dim3(16,2,16), 256, 0, stream>>>(zA, zfin);
            k_gemm<256,128,64,false,2><<<128, 256, 0, stream>>>(zfin, Wo + (size_t)k*32768, cb, nullptr, nullptr);
        }
        k_sub<<<1024, 256, 0, stream>>>(c2, c1, c);
    }

    k_pool<<<8, 128, 0, stream>>>(c, valid, pooled);
    k_fc<128, DFCN, true><<<16, 256, 0, stream>>>(pooled, fc0_w, fc0_b, f0);
    k_fc<DFCN, DFCN, true><<<16, 256, 0, stream>>>(f0, fc1_w, fc1_b, f1);
    k_fc2<<<1, 512, 0, stream>>>(f1, fc2_w, fc2_b, (float*)d_out);
}

// Round 7
// 1370.937 us; speedup vs baseline: 1.2141x; 1.2141x over previous
//
#include <hip/hip_runtime.h>
#include <math.h>

#define BB 8
#define NN 1024
#define DD 128
#define HH 2
#define LL 4
#define DFCN 512

typedef __attribute__((ext_vector_type(8))) short bf16x8;
typedef __attribute__((ext_vector_type(8))) _Float16 f16x8;
typedef __attribute__((ext_vector_type(4))) float f32x4;
typedef unsigned long long u64;
typedef unsigned short ushortT;

// fp32 -> bf16 (RNE) and back
static __device__ __forceinline__ unsigned short f2bf(float f) {
    unsigned u = __float_as_uint(f);
    u += 0x7FFF + ((u >> 16) & 1);
    return (unsigned short)(u >> 16);
}
static __device__ __forceinline__ float bf2f(unsigned short s) {
    return __uint_as_float(((unsigned)s) << 16);
}
// fp32 <-> fp16
static __device__ __forceinline__ unsigned short f2h(float f) {
    _Float16 h = (_Float16)f; return *(unsigned short*)&h;
}
static __device__ __forceinline__ float h2f(unsigned short u) {
    _Float16 h; *(unsigned short*)&h = u; return (float)h;
}

// ---------------------------------------------------------------------------
// Generic small-K GEMM (fp32 VALU): Y[M,NOUT] = X[M,K] @ W[K,NOUT]
// MODE 0: plain row-major fp32 out
// MODE 1: scatter out [B,N,H*D] -> [B,H,N,D] fp32 + bf16 hi/lo split outs
// MODE 2: gather input [B,H,N,D] -> [B,N,H*D] with relu on load
// MODE 3: row-major out as bf16 hi/lo split only (no fp32)
// ---------------------------------------------------------------------------
template<int K, int NOUT, int TM, bool RELU_OUT, int MODE>
__global__ __launch_bounds__(256) void k_gemm(const float* __restrict__ X,
                                              const float* __restrict__ W,
                                              float* __restrict__ Y,
                                              ushortT* __restrict__ O1,
                                              ushortT* __restrict__ O2) {
    constexpr int KC  = 32;
    constexpr int CT  = NOUT / 4;
    constexpr int RT  = 256 / CT;
    constexpr int RPT = TM / RT;
    __shared__ float Xs[TM][KC];
    __shared__ float Ws[KC][NOUT];
    const int t   = threadIdx.x;
    const int ct  = t % CT, rt = t / CT;
    const int row0 = blockIdx.x * TM;
    float acc[RPT][4];
#pragma unroll
    for (int r = 0; r < RPT; r++) { acc[r][0]=acc[r][1]=acc[r][2]=acc[r][3]=0.f; }

    for (int k0 = 0; k0 < K; k0 += KC) {
        constexpr int NX4 = TM * KC / 4;
#pragma unroll
        for (int p = 0; p < NX4 / 256; p++) {
            int idx = t + p * 256;
            int r = idx / (KC / 4), kg = idx % (KC / 4);
            int m = row0 + r;
            float4 v;
            if (MODE == 2) {
                int b = m / NN, n = m % NN;
                int hh = k0 / DD;
                int d  = (k0 % DD) + kg * 4;
                v = *(const float4*)&X[(((size_t)b * HH + hh) * NN + n) * DD + d];
                v.x = fmaxf(v.x, 0.f); v.y = fmaxf(v.y, 0.f);
                v.z = fmaxf(v.z, 0.f); v.w = fmaxf(v.w, 0.f);
            } else {
                v = *(const float4*)&X[(size_t)m * K + k0 + kg * 4];
            }
            *(float4*)&Xs[r][kg * 4] = v;
        }
        constexpr int NW4 = KC * NOUT / 4;
#pragma unroll
        for (int p = 0; p < NW4 / 256; p++) {
            int idx = t + p * 256;
            int kk = idx / (NOUT / 4), cg = idx % (NOUT / 4);
            *(float4*)&Ws[kk][cg * 4] =
                *(const float4*)&W[(size_t)(k0 + kk) * NOUT + cg * 4];
        }
        __syncthreads();
#pragma unroll
        for (int kk = 0; kk < KC; kk++) {
            float4 wv = *(const float4*)&Ws[kk][ct * 4];
#pragma unroll
            for (int r = 0; r < RPT; r++) {
                float xv = Xs[rt * RPT + r][kk];
                acc[r][0] += xv * wv.x; acc[r][1] += xv * wv.y;
                acc[r][2] += xv * wv.z; acc[r][3] += xv * wv.w;
            }
        }
        __syncthreads();
    }
#pragma unroll
    for (int r = 0; r < RPT; r++) {
        int m = row0 + rt * RPT + r;
        float4 v = make_float4(acc[r][0], acc[r][1], acc[r][2], acc[r][3]);
        if (RELU_OUT) {
            v.x = fmaxf(v.x, 0.f); v.y = fmaxf(v.y, 0.f);
            v.z = fmaxf(v.z, 0.f); v.w = fmaxf(v.w, 0.f);
        }
        if (MODE == 1) {
            int b = m / NN, n = m % NN;
            int o = ct * 4; int hh = o / DD, d = o % DD;
            size_t addr = (((size_t)b * HH + hh) * NN + n) * DD + d;
            *(float4*)&Y[addr] = v;
            ushort4 hi, lo;
            hi.x = f2bf(v.x); lo.x = f2bf(v.x - bf2f(hi.x));
            hi.y = f2bf(v.y); lo.y = f2bf(v.y - bf2f(hi.y));
            hi.z = f2bf(v.z); lo.z = f2bf(v.z - bf2f(hi.z));
            hi.w = f2bf(v.w); lo.w = f2bf(v.w - bf2f(hi.w));
            *(ushort4*)&O1[addr] = hi;
            *(ushort4*)&O2[addr] = lo;
        } else if (MODE == 3) {
            size_t addr = (size_t)m * NOUT + ct * 4;
            ushort4 hi, lo;
            hi.x = f2bf(v.x); lo.x = f2bf(v.x - bf2f(hi.x));
            hi.y = f2bf(v.y); lo.y = f2bf(v.y - bf2f(hi.y));
            hi.z = f2bf(v.z); lo.z = f2bf(v.z - bf2f(hi.z));
            hi.w = f2bf(v.w); lo.w = f2bf(v.w - bf2f(hi.w));
            *(ushort4*)&O1[addr] = hi;
            *(ushort4*)&O2[addr] = lo;
        } else {
            *(float4*)&Y[(size_t)m * NOUT + ct * 4] = v;
        }
    }
}

// ---------------------------------------------------------------------------
// e[j,k] = hW_j.h_k + h_j.hW_k via split-bf16 MFMA, e stored f16.
// Upper-triangle 64x64 tiles; BOTH triangle writes coalesced via LDS tiles
// (tileN normal + tileT transposed). XCD-partition swizzle: 2176 blocks =
// 8 XCDs x 272; each XCD owns exactly 2 bh slices (L2 locality).
// ---------------------------------------------------------------------------
__global__ __launch_bounds__(256) void k_esym_mfma(const ushortT* __restrict__ wHi,
                                                   const ushortT* __restrict__ wLo,
                                                   const ushortT* __restrict__ hHi,
                                                   const ushortT* __restrict__ hLo,
                                                   ushortT* __restrict__ e) {
    __shared__ ushortT smem[20480];   // 40 KB: 8 staging slices of 64*40
    ushortT* sWjHi = smem;
    ushortT* sWjLo = smem + 2560;
    ushortT* sHjHi = smem + 5120;
    ushortT* sHjLo = smem + 7680;
    ushortT* sWkHi = smem + 10240;
    ushortT* sWkLo = smem + 12800;
    ushortT* sHkHi = smem + 15360;
    ushortT* sHkLo = smem + 17920;

    // XCD partition: blocks round-robin across 8 XCDs by blockIdx%8 (m09).
    const int wgid = blockIdx.x;                  // 0..2175
    const int flat = (wgid & 7) * 272 + (wgid >> 3);
    const int bh = flat / 136;
    int idx = flat % 136, tj = 0;                 // tri index -> (tj,tk), tj<=tk
    while (idx >= 16 - tj) { idx -= 16 - tj; tj++; }
    const int tk = tj + idx;
    const int j0 = tj * 64, k0 = tk * 64;
    const int t = threadIdx.x;
    const int wave = t >> 6, lane = t & 63;
    const int wr = wave >> 1, wc = wave & 1;
    const int lrow = lane & 15, lg = lane >> 4;

    f32x4 acc[2][2];
#pragma unroll
    for (int m = 0; m < 2; m++)
#pragma unroll
        for (int n = 0; n < 2; n++) {
            acc[m][n][0] = 0.f; acc[m][n][1] = 0.f;
            acc[m][n][2] = 0.f; acc[m][n][3] = 0.f;
        }

    const size_t bhbase = (size_t)bh * NN * DD;

    for (int d0 = 0; d0 < DD; d0 += 32) {
        __syncthreads();
        {
            const int row = t >> 2, cu = (t & 3) * 8;
#define STAGE1(SRC, DST, BASE)                                                    \
            *(uint4*)&DST[row * 40 + cu] =                                        \
                *(const uint4*)&SRC[bhbase + (size_t)(BASE + row) * DD + d0 + cu];
            STAGE1(wHi, sWjHi, j0) STAGE1(wLo, sWjLo, j0)
            STAGE1(hHi, sHjHi, j0) STAGE1(hLo, sHjLo, j0)
            STAGE1(wHi, sWkHi, k0) STAGE1(wLo, sWkLo, k0)
            STAGE1(hHi, sHkHi, k0) STAGE1(hLo, sHkLo, k0)
#undef STAGE1
        }
        __syncthreads();

        bf16x8 a0[2], a1[2], b0[2], b1[2];
        // ---- group 1: A = hW_j, B = h_k ----
#pragma unroll
        for (int m = 0; m < 2; m++) {
            const int off = (wr * 32 + m * 16 + lrow) * 40 + lg * 8;
            a0[m] = *(const bf16x8*)&sWjHi[off];
            a1[m] = *(const bf16x8*)&sWjLo[off];
        }
#pragma unroll
        for (int n = 0; n < 2; n++) {
            const int off = (wc * 32 + n * 16 + lrow) * 40 + lg * 8;
            b0[n] = *(const bf16x8*)&sHkHi[off];
            b1[n] = *(const bf16x8*)&sHkLo[off];
        }
#pragma unroll
        for (int m = 0; m < 2; m++)
#pragma unroll
            for (int n = 0; n < 2; n++) {
                acc[m][n] = __builtin_amdgcn_mfma_f32_16x16x32_bf16(a0[m], b0[n], acc[m][n], 0, 0, 0);
                acc[m][n] = __builtin_amdgcn_mfma_f32_16x16x32_bf16(a0[m], b1[n], acc[m][n], 0, 0, 0);
                acc[m][n] = __builtin_amdgcn_mfma_f32_16x16x32_bf16(a1[m], b0[n], acc[m][n], 0, 0, 0);
            }
        // ---- group 2: A = h_j, B = hW_k ----
#pragma unroll
        for (int m = 0; m < 2; m++) {
            const int off = (wr * 32 + m * 16 + lrow) * 40 + lg * 8;
            a0[m] = *(const bf16x8*)&sHjHi[off];
            a1[m] = *(const bf16x8*)&sHjLo[off];
        }
#pragma unroll
        for (int n = 0; n < 2; n++) {
            const int off = (wc * 32 + n * 16 + lrow) * 40 + lg * 8;
            b0[n] = *(const bf16x8*)&sWkHi[off];
            b1[n] = *(const bf16x8*)&sWkLo[off];
        }
#pragma unroll
        for (int m = 0; m < 2; m++)
#pragma unroll
            for (int n = 0; n < 2; n++) {
                acc[m][n] = __builtin_amdgcn_mfma_f32_16x16x32_bf16(a0[m], b0[n], acc[m][n], 0, 0, 0);
                acc[m][n] = __builtin_amdgcn_mfma_f32_16x16x32_bf16(a0[m], b1[n], acc[m][n], 0, 0, 0);
                acc[m][n] = __builtin_amdgcn_mfma_f32_16x16x32_bf16(a1[m], b0[n], acc[m][n], 0, 0, 0);
            }
    }

    // -------- epilogue: f16 tile in LDS (both orientations), coalesced writes
    __syncthreads();                      // staging reads done; reuse smem
    ushortT* tileN = smem;                // [64][72]
    ushortT* tileT = smem + 4608;         // [64][72]
#pragma unroll
    for (int m = 0; m < 2; m++)
#pragma unroll
        for (int n = 0; n < 2; n++) {
            const int jlb = wr * 32 + m * 16 + lg * 4;
            const int kl  = wc * 32 + n * 16 + lrow;
            ushort4 tv;
            tv.x = f2h(acc[m][n][0]); tv.y = f2h(acc[m][n][1]);
            tv.z = f2h(acc[m][n][2]); tv.w = f2h(acc[m][n][3]);
            tileN[(jlb + 0) * 72 + kl] = tv.x;
            tileN[(jlb + 1) * 72 + kl] = tv.y;
            tileN[(jlb + 2) * 72 + kl] = tv.z;
            tileN[(jlb + 3) * 72 + kl] = tv.w;
            *(ushort4*)&tileT[kl * 72 + jlb] = tv;
        }
    __syncthreads();
#pragma unroll
    for (int it = 0; it < 4; it++) {
        const int i2 = t + it * 256;
        const int row = i2 >> 4, ch = (i2 & 15) * 4;   // uint2 = 4 ushorts
        *(uint2*)&e[((size_t)bh * NN + j0 + row) * NN + k0 + ch] =
            *(const uint2*)&tileN[row * 72 + ch];
        if (tj != tk)
            *(uint2*)&e[((size_t)bh * NN + k0 + row) * NN + j0 + ch] =
                *(const uint2*)&tileT[row * 72 + ch];
    }
}

// ---------------------------------------------------------------------------
// Column nnz bitmask build (atomic-free). bits[b][k][t] bit jj <=> adj[b][64t+jj][k]!=0
// ---------------------------------------------------------------------------
__global__ __launch_bounds__(256) void k_buildT(const float* __restrict__ adj,
                                                u64* __restrict__ bits) {
    const int gid = blockIdx.x * 256 + threadIdx.x;   // 8*16*1024
    const int k  = gid & 1023;
    const int tw = (gid >> 10) & 15;
    const int b  = gid >> 14;
    const float* ac = adj + ((size_t)b << 20) + k;
    u64 w = 0;
#pragma unroll 8
    for (int jj = 0; jj < 64; jj++) {
        if (ac[(size_t)(tw * 64 + jj) << 10] != 0.f) w |= 1ull << jj;
    }
    bits[((size_t)((b << 10) | k)) * 16 + tw] = w;
}

// per-column popcount
__global__ __launch_bounds__(256) void k_cnt(const u64* __restrict__ bits,
                                             int* __restrict__ ccnt) {
    const int gid = blockIdx.x * 256 + threadIdx.x;   // 8192
    const u64* wb = bits + (size_t)gid * 16;
    int c = 0;
#pragma unroll
    for (int tw = 0; tw < 16; tw++) c += __popcll(wb[tw]);
    ccnt[gid] = c;
}

// ---------------------------------------------------------------------------
// Softmax pass A: partial online max/sum per (bh, 4-col group, 16-row chunk).
// e is f16 now.
// ---------------------------------------------------------------------------
__global__ __launch_bounds__(256) void k_smA(const ushortT* __restrict__ e,
                                             const u64* __restrict__ bits,
                                             float* __restrict__ pm,
                                             float* __restrict__ ps) {
    const int gid = blockIdx.x * 256 + threadIdx.x;   // 16*64*256
    const int kg = gid & 255;
    const int jc = (gid >> 8) & 63;
    const int bh = gid >> 14;
    const int b  = bh >> 1;
    const int k4 = kg * 4;
    const int tw = jc >> 2;
    const int bo = (jc & 3) * 16;
    u64 w[4];
#pragma unroll
    for (int i = 0; i < 4; i++)
        w[i] = bits[((size_t)((b << 10) | (k4 + i))) * 16 + tw];
    const ushortT* ec = e + ((size_t)bh << 20) + (size_t)(jc * 16) * NN + k4;
    float m[4] = {0.f, 0.f, 0.f, 0.f};
    float s[4] = {0.f, 0.f, 0.f, 0.f};
#pragma unroll
    for (int r = 0; r < 16; r++) {
        const ushort4 ev = *(const ushort4*)&ec[(size_t)r * NN];
        const float evs[4] = {h2f(ev.x), h2f(ev.y), h2f(ev.z), h2f(ev.w)};
#pragma unroll
        for (int i = 0; i < 4; i++) {
            const bool on = (w[i] >> (bo + r)) & 1;
            const float v = on ? evs[i] : 0.f;
            const float mn = fmaxf(m[i], v);
            s[i] = s[i] * __expf(m[i] - mn) + (on ? __expf(v - mn) : 0.f);
            m[i] = mn;
        }
    }
    const size_t o = (((size_t)bh * 64 + jc) << 10) + k4;
    *(float4*)&pm[o] = make_float4(m[0], m[1], m[2], m[3]);
    *(float4*)&ps[o] = make_float4(s[0], s[1], s[2], s[3]);
}

// Softmax pass B: wave-parallel combine of 64 partials per column.
__global__ __launch_bounds__(256) void k_smB(const float* __restrict__ pm,
                                             const float* __restrict__ ps,
                                             const int* __restrict__ ccnt,
                                             float* __restrict__ smax,
                                             float* __restrict__ sdinv) {
    __shared__ float lm[4][64], ls[4][64];
    const int t = threadIdx.x, q = t >> 6, lane = t & 63;
    const int colg = blockIdx.x * 64 + lane;
    const int bh = colg >> 10, k = colg & 1023;
    const int b  = bh >> 1;
    float M = 0.f, S = 0.f;
#pragma unroll 4
    for (int i = 0; i < 16; i++) {
        const int jc = q * 16 + i;
        const size_t o = (((size_t)bh * 64 + jc) << 10) + k;
        const float pmv = pm[o], psv = ps[o];
        const float mn = fmaxf(M, pmv);
        S = S * __expf(M - mn) + psv * __expf(pmv - mn);
        M = mn;
    }
    lm[q][lane] = M; ls[q][lane] = S;
    __syncthreads();
    if (q == 0) {
#pragma unroll
        for (int qq = 1; qq < 4; qq++) {
            const float pmv = lm[qq][lane], psv = ls[qq][lane];
            const float mn = fmaxf(M, pmv);
            S = S * __expf(M - mn) + psv * __expf(pmv - mn);
            M = mn;
        }
        S += (float)(NN - ccnt[(b << 10) + k]) * __expf(-M);
        smax[colg] = M;
        sdinv[colg] = 1.f / S;
    }
}

// Softmax pass C: dense f16 att write from f16 e.
__global__ __launch_bounds__(256) void k_smC(const ushortT* __restrict__ e,
                                             const u64* __restrict__ bits,
                                             const float* __restrict__ smax,
                                             const float* __restrict__ sdinv,
                                             ushortT* __restrict__ att) {
    const int gid = blockIdx.x * 256 + threadIdx.x;
    const int kg = gid & 255;
    const int jc = (gid >> 8) & 63;
    const int bh = gid >> 14;
    const int b  = bh >> 1;
    const int k4 = kg * 4;
    const int tw = jc >> 2;
    const int bo = (jc & 3) * 16;
    u64 w[4];
#pragma unroll
    for (int i = 0; i < 4; i++)
        w[i] = bits[((size_t)((b << 10) | (k4 + i))) * 16 + tw];
    const float4 m4 = *(const float4*)&smax[(bh << 10) + k4];
    const float4 d4 = *(const float4*)&sdinv[(bh << 10) + k4];
    const float ms[4] = {m4.x, m4.y, m4.z, m4.w};
    const float ds[4] = {d4.x, d4.y, d4.z, d4.w};
    const ushortT* ec = e + ((size_t)bh << 20) + (size_t)(jc * 16) * NN + k4;
    ushortT* ac = att + ((size_t)bh << 20) + (size_t)(jc * 16) * NN + k4;
#pragma unroll
    for (int r = 0; r < 16; r++) {
        const ushort4 ev = *(const ushort4*)&ec[(size_t)r * NN];
        const float evs[4] = {h2f(ev.x), h2f(ev.y), h2f(ev.z), h2f(ev.w)};
        ushort4 o;
        ushortT os[4];
#pragma unroll
        for (int i = 0; i < 4; i++) {
            const bool on = (w[i] >> (bo + r)) & 1;
            os[i] = f2h(on ? __expf(evs[i] - ms[i]) * ds[i] : 0.f);
        }
        o.x = os[0]; o.y = os[1]; o.z = os[2]; o.w = os[3];
        *(ushort4*)&ac[(size_t)r * NN] = o;
    }
}

// ---------------------------------------------------------------------------
// Transpose h fp32 [bh][n][d] -> hT f16 [bh][d][n]
// ---------------------------------------------------------------------------
__global__ __launch_bounds__(256) void k_trT(const float* __restrict__ h,
                                             ushortT* __restrict__ hT) {
    __shared__ float tile[64][65];
    const int bh = blockIdx.z;
    const int n0 = blockIdx.x * 64, d0 = blockIdx.y * 64;
    const int t = threadIdx.x;
#pragma unroll
    for (int q = 0; q < 16; q++) {
        const int idx = t + q * 256;
        const int row = idx >> 6, col = idx & 63;
        tile[row][col] = h[(size_t)bh * 131072 + (size_t)(n0 + row) * DD + d0 + col];
    }
    __syncthreads();
#pragma unroll
    for (int q = 0; q < 16; q++) {
        const int idx = t + q * 256;
        const int row = idx >> 6, col = idx & 63;
        hT[(size_t)bh * 131072 + (size_t)(d0 + row) * NN + n0 + col] = f2h(tile[col][row]);
    }
}

// Transpose zT f16 [bh][d][n] -> zfin fp32 [bh][n][d]
__global__ __launch_bounds__(256) void k_fin(const ushortT* __restrict__ zT,
                                             float* __restrict__ zfin) {
    __shared__ float tile[64][65];
    const int bh = blockIdx.z;
    const int n0 = blockIdx.x * 64, d0 = blockIdx.y * 64;
    const int t = threadIdx.x;
#pragma unroll
    for (int q = 0; q < 16; q++) {
        const int idx = t + q * 256;
        const int row = idx >> 6, col = idx & 63;
        tile[row][col] = h2f(zT[(size_t)bh * 131072 + (size_t)(d0 + row) * NN + n0 + col]);
    }
    __syncthreads();
#pragma unroll
    for (int q = 0; q < 16; q++) {
        const int idx = t + q * 256;
        const int row = idx >> 6, col = idx & 63;
        zfin[(size_t)bh * 131072 + (size_t)(n0 + row) * DD + d0 + col] = tile[col][row];
    }
}

// ---------------------------------------------------------------------------
// Dense f16 MFMA hop (round-5 proven version): out = relu(att @ zinT),
// optional fused beta-mix, transposed output write. 64-row i-tiles.
// ---------------------------------------------------------------------------
template<bool FUSED>
__global__ __launch_bounds__(256) void k_hop(const ushortT* __restrict__ att,
                                             const ushortT* __restrict__ zin,
                                             const ushortT* __restrict__ hT,
                                             const float* __restrict__ beta,
                                             ushortT* __restrict__ zout) {
    __shared__ ushortT sA[64 * 72];
    __shared__ ushortT sB[128 * 72];
    const int bh = blockIdx.y;
    const int i0 = blockIdx.x * 64;
    const int t = threadIdx.x, wave = t >> 6, lane = t & 63;
    const int wr = wave >> 1, wc = wave & 1;
    const int lrow = lane & 15, lg = lane >> 4;
    const ushortT* attb = att + ((size_t)bh << 20);
    const ushortT* zb   = zin + (size_t)bh * 131072;

    f32x4 acc[2][4];
#pragma unroll
    for (int m = 0; m < 2; m++)
#pragma unroll
        for (int n = 0; n < 4; n++) {
            acc[m][n][0]=0.f; acc[m][n][1]=0.f; acc[m][n][2]=0.f; acc[m][n][3]=0.f;
        }

    for (int j0 = 0; j0 < NN; j0 += 64) {
        __syncthreads();
#pragma unroll
        for (int q = 0; q < 2; q++) {
            const int u = t + q * 256;
            const int row = u >> 3, c8 = (u & 7) * 8;
            *(uint4*)&sA[row * 72 + c8] =
                *(const uint4*)&attb[(size_t)(i0 + row) * NN + j0 + c8];
        }
#pragma unroll
        for (int q = 0; q < 4; q++) {
            const int u = t + q * 256;
            const int row = u >> 3, c8 = (u & 7) * 8;
            *(uint4*)&sB[row * 72 + c8] =
                *(const uint4*)&zb[(size_t)row * NN + j0 + c8];
        }
        __syncthreads();
#pragma unroll
        for (int ks = 0; ks < 2; ks++) {
            f16x8 a[2], b[4];
#pragma unroll
            for (int m = 0; m < 2; m++)
                a[m] = *(const f16x8*)&sA[(wr * 32 + m * 16 + lrow) * 72 + ks * 32 + lg * 8];
#pragma unroll
            for (int n = 0; n < 4; n++)
                b[n] = *(const f16x8*)&sB[(wc * 64 + n * 16 + lrow) * 72 + ks * 32 + lg * 8];
#pragma unroll
            for (int m = 0; m < 2; m++)
#pragma unroll
                for (int n = 0; n < 4; n++)
                    acc[m][n] = __builtin_amdgcn_mfma_f32_16x16x32_f16(a[m], b[n], acc[m][n], 0, 0, 0);
        }
    }

    const float* betab = beta + ((size_t)bh << 10);
    const ushortT* hTb = hT + (size_t)bh * 131072;
    ushortT* zo = zout + (size_t)bh * 131072;
#pragma unroll
    for (int m = 0; m < 2; m++)
#pragma unroll
        for (int n = 0; n < 4; n++) {
            const int d = wc * 64 + n * 16 + lrow;
            const int i = i0 + wr * 32 + m * 16 + lg * 4;
            ushort4 o;
            float vq[4];
            if (FUSED) {
                const float4 bev = *(const float4*)&betab[i];
                const ushort4 hv = *(const ushort4*)&hTb[(size_t)d * NN + i];
                vq[0] = bev.x * h2f(hv.x) + (1.f - bev.x) * fmaxf(acc[m][n][0], 0.f);
                vq[1] = bev.y * h2f(hv.y) + (1.f - bev.y) * fmaxf(acc[m][n][1], 0.f);
                vq[2] = bev.z * h2f(hv.z) + (1.f - bev.z) * fmaxf(acc[m][n][2], 0.f);
                vq[3] = bev.w * h2f(hv.w) + (1.f - bev.w) * fmaxf(acc[m][n][3], 0.f);
            } else {
                vq[0] = fmaxf(acc[m][n][0], 0.f); vq[1] = fmaxf(acc[m][n][1], 0.f);
                vq[2] = fmaxf(acc[m][n][2], 0.f); vq[3] = fmaxf(acc[m][n][3], 0.f);
            }
            o.x = f2h(vq[0]); o.y = f2h(vq[1]); o.z = f2h(vq[2]); o.w = f2h(vq[3]);
            *(ushort4*)&zo[(size_t)d * NN + i] = o;
        }
}

// beta partials: thread per (dchunk of 32, bh, n); pb[dc][bh][n]
__global__ __launch_bounds__(256) void k_betaA(const ushortT* __restrict__ hT,
                                               const ushortT* __restrict__ azT,
                                               const float* __restrict__ Wbw,
                                               float* __restrict__ pb) {
    const int gid = blockIdx.x * 256 + threadIdx.x;   // 65536
    const int n  = gid & 1023;
    const int bh = (gid >> 10) & 15;
    const int dc = gid >> 14;                         // 0..3
    const size_t base = (size_t)bh * 131072 + ((size_t)(dc * 32) << 10) + n;
    const ushortT* hp = hT  + base;
    const ushortT* ap = azT + base;
    float s = 0.f;
#pragma unroll 8
    for (int d = 0; d < 32; d++)
        s += h2f(hp[(size_t)d << 10]) * Wbw[dc * 32 + d]
           + h2f(ap[(size_t)d << 10]) * Wbw[DD + dc * 32 + d];
    pb[gid] = s;
}

__global__ __launch_bounds__(256) void k_betaB(const float* __restrict__ pb,
                                               const float* __restrict__ Wbb,
                                               float* __restrict__ beta) {
    const int gid = blockIdx.x * 256 + threadIdx.x;   // 16384
    const float s = pb[gid] + pb[gid + 16384] + pb[gid + 32768] + pb[gid + 49152];
    beta[gid] = 1.f / (1.f + expf(-(s + Wbb[0])));
}

// zT = beta*hT + (1-beta)*azT
__global__ __launch_bounds__(256) void k_zupT(const ushortT* __restrict__ hT,
                                              const ushortT* __restrict__ azT,
                                              const float* __restrict__ beta,
                                              ushortT* __restrict__ zT) {
    const int gid = blockIdx.x * 256 + threadIdx.x;
    const size_t base = (size_t)gid * 8;
    const int n0 = (int)(base & 1023);
    const int bh = (int)(base >> 17);
    ushortT hu[8], au[8], ou[8];
    *(uint4*)hu = *(const uint4*)&hT[base];
    *(uint4*)au = *(const uint4*)&azT[base];
    const float4 b0 = *(const float4*)&beta[(bh << 10) + n0];
    const float4 b1 = *(const float4*)&beta[(bh << 10) + n0 + 4];
    const float be[8] = {b0.x, b0.y, b0.z, b0.w, b1.x, b1.y, b1.z, b1.w};
#pragma unroll
    for (int i = 0; i < 8; i++)
        ou[i] = f2h(be[i] * h2f(hu[i]) + (1.f - be[i]) * h2f(au[i]));
    *(uint4*)&zT[base] = *(uint4*)ou;
}

__global__ __launch_bounds__(256) void k_sub(const float* __restrict__ c2,
                                             const float* __restrict__ c1,
                                             float* __restrict__ c) {
    const int g = blockIdx.x * 256 + threadIdx.x;
    const float4 a = ((const float4*)c2)[g];
    const float4 b = ((const float4*)c1)[g];
    ((float4*)c)[g] = make_float4(a.x - b.x, a.y - b.y, a.z - b.z, a.w - b.w);
}

__global__ void k_pool(const float* __restrict__ c, const float* __restrict__ valid,
                       float* __restrict__ pooled) {
    const int b = blockIdx.x, d = threadIdx.x;
    const float* cb = c + (size_t)b * NN * DD;
    const float* vb = valid + (size_t)b * NN;
    float s = 0.f, sv = 0.f;
    for (int n = 0; n < NN; n++) { float v = vb[n]; s += cb[(size_t)n * DD + d] * v; sv += v; }
    pooled[b * DD + d] = s / sv;
}

template<int K, int NOUT, bool RELU>
__global__ void k_fc(const float* __restrict__ X, const float* __restrict__ W,
                     const float* __restrict__ bias, float* __restrict__ Y) {
    const int gid = blockIdx.x * blockDim.x + threadIdx.x;
    if (gid >= BB * NOUT) return;
    const int b = gid / NOUT, o = gid % NOUT;
    float s = bias[o];
    for (int i = 0; i < K; i++) s += X[(size_t)b * K + i] * W[(size_t)i * NOUT + o];
    Y[gid] = RELU ? fmaxf(s, 0.f) : s;
}

__global__ void k_fc2(const float* __restrict__ X, const float* __restrict__ W,
                      const float* __restrict__ bias, float* __restrict__ out) {
    const int b = threadIdx.x >> 6, lane = threadIdx.x & 63;
    float s = 0.f;
    for (int i = lane; i < DFCN; i += 64) s += X[(size_t)b * DFCN + i] * W[i];
#pragma unroll
    for (int off = 32; off > 0; off >>= 1) s += __shfl_down(s, off);
    if (lane == 0) out[b] = 1.f / (1.f + expf(-(s + bias[0])));
}

// ---------------------------------------------------------------------------
extern "C" void kernel_launch(void* const* d_in, const int* in_sizes, int n_in,
                              void* d_out, int out_size, void* d_ws, size_t ws_size,
                              hipStream_t stream) {
    const float* x        = (const float*)d_in[0];
    const float* adj1     = (const float*)d_in[1];
    const float* adj2     = (const float*)d_in[2];
    const float* valid    = (const float*)d_in[3];
    const float* embede_w = (const float*)d_in[4];
    const float* Wh       = (const float*)d_in[5];
    const float* We       = (const float*)d_in[6];
    const float* Wbw      = (const float*)d_in[7];
    const float* Wbb      = (const float*)d_in[8];
    const float* Wo       = (const float*)d_in[9];
    const float* fc0_w    = (const float*)d_in[10];
    const float* fc0_b    = (const float*)d_in[11];
    const float* fc1_w    = (const float*)d_in[12];
    const float* fc1_b    = (const float*)d_in[13];
    const float* fc2_w    = (const float*)d_in[14];
    const float* fc2_b    = (const float*)d_in[15];

    // ---- workspace carve: ~136 MB ----
    float* ws = (float*)d_ws;
    float* c      = ws;                          // 1,048,576 f
    float* h      = c      + (size_t)1048576;    // 2,097,152 f
    float* c1     = h      + (size_t)2097152;    // 1,048,576 f
    float* c2     = c1     + (size_t)1048576;    // 1,048,576 f
    float* zfin   = c2     + (size_t)1048576;    // 2,097,152 f
    float* beta   = zfin   + (size_t)2097152;    // 16,384 f
    float* pm     = beta   + (size_t)16384;      // 1,048,576 f
    float* ps     = pm     + (size_t)1048576;    // 1,048,576 f
    float* smax   = ps     + (size_t)1048576;    // 16,384 f
    float* sdinv  = smax   + (size_t)16384;      // 16,384 f
    float* pb     = sdinv  + (size_t)16384;      // 65,536 f
    float* pooled = pb     + (size_t)65536;      // 1,024 f
    float* f0     = pooled + (size_t)1024;       // 4,096 f
    float* f1     = f0     + (size_t)4096;       // 4,096 f
    ushortT* hHi  = (ushortT*)(f1 + 4096);       // 2,097,152 us each
    ushortT* hLo  = hHi + (size_t)2097152;
    ushortT* wHi  = hLo + (size_t)2097152;
    ushortT* wLo  = wHi + (size_t)2097152;
    ushortT* hT   = wLo + (size_t)2097152;
    ushortT* zTa  = hT  + (size_t)2097152;
    ushortT* zTb  = zTa + (size_t)2097152;       // also serves as azT
    ushortT* att  = zTb + (size_t)2097152;       // 16,777,216 us
    ushortT* e    = att + (size_t)16777216;      // 16,777,216 us (f16 now)
    u64* bits1    = (u64*)(e + (size_t)16777216);
    u64* bits2    = bits1 + (size_t)131072;
    int* ccnt1    = (int*)(bits2 + (size_t)131072);
    int* ccnt2    = ccnt1 + 8192;

    k_buildT<<<512, 256, 0, stream>>>(adj1, bits1);
    k_buildT<<<512, 256, 0, stream>>>(adj2, bits2);
    k_cnt<<<32, 256, 0, stream>>>(bits1, ccnt1);
    k_cnt<<<32, 256, 0, stream>>>(bits2, ccnt2);

    // c = x @ embede_w
    k_gemm<128,128,64,false,0><<<128, 256, 0, stream>>>(x, embede_w, c, nullptr, nullptr);

    for (int k = 0; k < LL; k++) {
        const int nhop = k + 1;
        k_gemm<128,256,32,true,1><<<256, 256, 0, stream>>>(c, Wh + (size_t)k*32768, h, hHi, hLo);
        k_gemm<128,128,64,false,3><<<256, 256, 0, stream>>>(h, We + (size_t)k*16384, nullptr, wHi, wLo);
        k_trT<<<dim3(16,2,16), 256, 0, stream>>>(h, hT);
        // symmetric e (f16), upper-tri tiles, coalesced dual write, XCD-partitioned
        k_esym_mfma<<<2176, 256, 0, stream>>>(wHi, wLo, hHi, hLo, e);

        for (int br = 0; br < 2; br++) {
            const u64* bits = (br == 0) ? bits1 : bits2;
            const int* ccnt = (br == 0) ? ccnt1 : ccnt2;
            float*     cb   = (br == 0) ? c1    : c2;

            k_smA<<<1024, 256, 0, stream>>>(e, bits, pm, ps);
            k_smB<<<256, 256, 0, stream>>>(pm, ps, ccnt, smax, sdinv);
            k_smC<<<1024, 256, 0, stream>>>(e, bits, smax, sdinv, att);

            k_hop<false><<<dim3(16,16), 256, 0, stream>>>(att, hT, hT, beta, zTb);
            k_betaA<<<256, 256, 0, stream>>>(hT, zTb, Wbw + (size_t)k*256, pb);
            k_betaB<<<64, 256, 0, stream>>>(pb, Wbb + k, beta);
            k_zupT<<<1024, 256, 0, stream>>>(hT, zTb, beta, zTa);
            ushortT* zA = zTa; ushortT* zB = zTb;
            for (int tpp = 1; tpp < nhop; tpp++) {
                k_hop<true><<<dim3(16,16), 256, 0, stream>>>(att, zA, hT, beta, zB);
                ushortT* tmp = zA; zA = zB; zB = tmp;
            }
            k_fin<<<dim3(16,2,16), 256, 0, stream>>>(zA, zfin);
            k_gemm<256,128,64,false,2><<<128, 256, 0, stream>>>(zfin, Wo + (size_t)k*32768, cb, nullptr, nullptr);
        }
        k_sub<<<1024, 256, 0, stream>>>(c2, c1, c);
    }

    k_pool<<<8, 128, 0, stream>>>(c, valid, pooled);
    k_fc<128, DFCN, true><<<16, 256, 0, stream>>>(pooled, fc0_w, fc0_b, f0);
    k_fc<DFCN, DFCN, true><<<16, 256, 0, stream>>>(f0, fc1_w, fc1_b, f1);
    k_fc2<<<1, 512, 0, stream>>>(f1, fc2_w, fc2_b, (float*)d_out);
}

// Round 8
// 1159.392 us; speedup vs baseline: 1.4356x; 1.1825x over previous
//
#include <hip/hip_runtime.h>
#include <math.h>

#define BB 8
#define NN 1024
#define DD 128
#define HH 2
#define LL 4
#define DFCN 512

typedef __attribute__((ext_vector_type(8))) short bf16x8;
typedef __attribute__((ext_vector_type(8))) _Float16 f16x8;
typedef __attribute__((ext_vector_type(4))) float f32x4;
typedef unsigned long long u64;
typedef unsigned short ushortT;

static __device__ __forceinline__ unsigned short f2bf(float f) {
    unsigned u = __float_as_uint(f);
    u += 0x7FFF + ((u >> 16) & 1);
    return (unsigned short)(u >> 16);
}
static __device__ __forceinline__ float bf2f(unsigned short s) {
    return __uint_as_float(((unsigned)s) << 16);
}
static __device__ __forceinline__ unsigned short f2h(float f) {
    _Float16 h = (_Float16)f; return *(unsigned short*)&h;
}
static __device__ __forceinline__ float h2f(unsigned short u) {
    _Float16 h; *(unsigned short*)&h = u; return (float)h;
}

// ---------------------------------------------------------------------------
// Weight pre-split: W[l][k][n] fp32 -> WT hi/lo [l][n][k] bf16 (32x32 tiles)
// ---------------------------------------------------------------------------
template<int K, int N>
__global__ __launch_bounds__(256) void k_splitWT(const float* __restrict__ W,
                                                 ushortT* __restrict__ Thi,
                                                 ushortT* __restrict__ Tlo) {
    __shared__ float tile[32][33];
    const int l = blockIdx.z;
    const int n0 = blockIdx.x * 32, k0 = blockIdx.y * 32;
    const float* Wl = W + (size_t)l * K * N;
    ushortT* Hl = Thi + (size_t)l * K * N;
    ushortT* Ll = Tlo + (size_t)l * K * N;
    const int t = threadIdx.x;
    const int r = t >> 5, cc = t & 31;
#pragma unroll
    for (int q = 0; q < 4; q++)
        tile[r + q * 8][cc] = Wl[(size_t)(k0 + r + q * 8) * N + n0 + cc];
    __syncthreads();
#pragma unroll
    for (int q = 0; q < 4; q++) {
        const int nl = r + q * 8, kl = cc;
        const float v = tile[kl][nl];
        const ushortT hi = f2bf(v);
        Hl[(size_t)(n0 + nl) * K + k0 + kl] = hi;
        Ll[(size_t)(n0 + nl) * K + k0 + kl] = f2bf(v - bf2f(hi));
    }
}

// ---------------------------------------------------------------------------
// Unified split-bf16 MFMA GEMM: Y[M,N] = A[M,K] @ W[K,N] (6-term Markidis).
// B = pre-split transposed weights [N][K]. 4 waves split N; TM rows shared.
// IN_MODE  0: A = hi/lo row-major [M][K]
//          1: A = hi/lo gathered (Wo): m=(b,n), k=(hh,d) -> [(b*2+hh)][n][d]
//          2: A = fp32 row-major, split during staging (embede)
// OUT_MODE 0: Yf fp32 row-major
//          1: scatter [b][n][hh*128+d] -> h fp32 [bh][n][d] + splits (Wh)
//          2: splits row-major only (We)
//          3: Yf fp32 + splits row-major (embede)
// LDS epilogue -> all global writes coalesced full rows.
// ---------------------------------------------------------------------------
template<int K, int N, int TM, bool RELU, int IN_MODE, int OUT_MODE>
__global__ __launch_bounds__(256) void k_mgemm(const ushortT* __restrict__ Ahi,
                                               const ushortT* __restrict__ Alo,
                                               const float* __restrict__ Afp,
                                               const ushortT* __restrict__ BThi,
                                               const ushortT* __restrict__ BTlo,
                                               float* __restrict__ Yf,
                                               ushortT* __restrict__ O1,
                                               ushortT* __restrict__ O2) {
    constexpr int MF = TM / 16;
    constexpr int NW = N / 4;
    constexpr int NF = NW / 16;
    constexpr int SSTG = (TM + N) * 160;          // staging bytes (hi+lo A,B)
    constexpr int SEPI = TM * (N + 8) * 4;        // epilogue fp32 tile
    constexpr int SMEM = SSTG > SEPI ? SSTG : SEPI;
    __shared__ char smem[SMEM];
    ushortT* sAhi = (ushortT*)smem;               // [TM][40]
    ushortT* sAlo = sAhi + TM * 40;
    ushortT* sBhi = sAlo + TM * 40;               // [N][40]
    ushortT* sBlo = sBhi + (size_t)N * 40;
    const int t = threadIdx.x;
    const int wave = t >> 6, lane = t & 63;
    const int lrow = lane & 15, lg = lane >> 4;
    const int row0 = blockIdx.x * TM;

    f32x4 acc[MF][NF];
#pragma unroll
    for (int m = 0; m < MF; m++)
#pragma unroll
        for (int n = 0; n < NF; n++) {
            acc[m][n][0]=0.f; acc[m][n][1]=0.f; acc[m][n][2]=0.f; acc[m][n][3]=0.f;
        }

    for (int k0 = 0; k0 < K; k0 += 32) {
        __syncthreads();
        // ---- stage A ----
        if (IN_MODE == 2) {
#pragma unroll
            for (int p = 0; p < TM * 8 / 256; p++) {
                const int idx = t + p * 256;
                const int row = idx >> 3, cu = (idx & 7) * 4;
                const float4 v = *(const float4*)&Afp[(size_t)(row0 + row) * K + k0 + cu];
                ushort4 hi, lo;
                hi.x = f2bf(v.x); lo.x = f2bf(v.x - bf2f(hi.x));
                hi.y = f2bf(v.y); lo.y = f2bf(v.y - bf2f(hi.y));
                hi.z = f2bf(v.z); lo.z = f2bf(v.z - bf2f(hi.z));
                hi.w = f2bf(v.w); lo.w = f2bf(v.w - bf2f(hi.w));
                *(ushort4*)&sAhi[row * 40 + cu] = hi;
                *(ushort4*)&sAlo[row * 40 + cu] = lo;
            }
        } else {
#pragma unroll
            for (int p = 0; p < TM * 8 / 256; p++) {
                const int idx = t + p * 256;
                const bool ishi = idx < TM * 4;
                const int i2 = ishi ? idx : idx - TM * 4;
                const int row = i2 >> 2, cu = (i2 & 3) * 8;
                size_t ga;
                if (IN_MODE == 0) {
                    ga = (size_t)(row0 + row) * K + k0 + cu;
                } else {
                    const int m = row0 + row;
                    const int b = m >> 10, n = m & 1023;
                    const int hh = k0 >> 7, d = (k0 & 127) + cu;
                    ga = (((size_t)(b * 2 + hh) << 10) + n) * DD + d;
                }
                const ushortT* src = ishi ? Ahi : Alo;
                ushortT* dst = ishi ? sAhi : sAlo;
                *(uint4*)&dst[row * 40 + cu] = *(const uint4*)&src[ga];
            }
        }
        // ---- stage B ----
#pragma unroll
        for (int p = 0; p < N / 32; p++) {
            const int idx = t + p * 256;
            const bool ishi = idx < N * 4;
            const int i2 = ishi ? idx : idx - N * 4;
            const int row = i2 >> 2, cu = (i2 & 3) * 8;
            const ushortT* src = ishi ? BThi : BTlo;
            ushortT* dst = ishi ? sBhi : sBlo;
            *(uint4*)&dst[row * 40 + cu] = *(const uint4*)&src[(size_t)row * K + k0 + cu];
        }
        __syncthreads();
        // ---- MFMA ----
        bf16x8 a0[MF], a1[MF], b0[NF], b1[NF];
#pragma unroll
        for (int m = 0; m < MF; m++) {
            const int off = (m * 16 + lrow) * 40 + lg * 8;
            a0[m] = *(const bf16x8*)&sAhi[off];
            a1[m] = *(const bf16x8*)&sAlo[off];
        }
#pragma unroll
        for (int n = 0; n < NF; n++) {
            const int off = (wave * NW + n * 16 + lrow) * 40 + lg * 8;
            b0[n] = *(const bf16x8*)&sBhi[off];
            b1[n] = *(const bf16x8*)&sBlo[off];
        }
#pragma unroll
        for (int m = 0; m < MF; m++)
#pragma unroll
            for (int n = 0; n < NF; n++) {
                acc[m][n] = __builtin_amdgcn_mfma_f32_16x16x32_bf16(a0[m], b0[n], acc[m][n], 0, 0, 0);
                acc[m][n] = __builtin_amdgcn_mfma_f32_16x16x32_bf16(a0[m], b1[n], acc[m][n], 0, 0, 0);
                acc[m][n] = __builtin_amdgcn_mfma_f32_16x16x32_bf16(a1[m], b0[n], acc[m][n], 0, 0, 0);
            }
    }

    // ---- epilogue via LDS (coalesced) ----
    __syncthreads();
    float* tile = (float*)smem;                   // [TM][N+8]
#pragma unroll
    for (int m = 0; m < MF; m++)
#pragma unroll
        for (int n = 0; n < NF; n++) {
            const int col = wave * NW + n * 16 + lrow;
#pragma unroll
            for (int q = 0; q < 4; q++)
                tile[(m * 16 + lg * 4 + q) * (N + 8) + col] = acc[m][n][q];
        }
    __syncthreads();
#pragma unroll
    for (int p = 0; p < TM * N / 1024; p++) {
        const int idx = t + p * 256;
        const int row = idx / (N / 4), cg = idx % (N / 4);
        float4 v = *(const float4*)&tile[row * (N + 8) + cg * 4];
        if (RELU) {
            v.x = fmaxf(v.x, 0.f); v.y = fmaxf(v.y, 0.f);
            v.z = fmaxf(v.z, 0.f); v.w = fmaxf(v.w, 0.f);
        }
        const int m = row0 + row;
        if (OUT_MODE == 0) {
            *(float4*)&Yf[(size_t)m * N + cg * 4] = v;
        } else {
            ushort4 hi, lo;
            hi.x = f2bf(v.x); lo.x = f2bf(v.x - bf2f(hi.x));
            hi.y = f2bf(v.y); lo.y = f2bf(v.y - bf2f(hi.y));
            hi.z = f2bf(v.z); lo.z = f2bf(v.z - bf2f(hi.z));
            hi.w = f2bf(v.w); lo.w = f2bf(v.w - bf2f(hi.w));
            if (OUT_MODE == 1) {
                const int b = m >> 10, n = m & 1023;
                const int col = cg * 4;
                const int hh = col >> 7, d = col & 127;
                const size_t addr = (((size_t)(b * 2 + hh) << 10) + n) * DD + d;
                *(float4*)&Yf[addr] = v;
                *(ushort4*)&O1[addr] = hi;
                *(ushort4*)&O2[addr] = lo;
            } else {
                const size_t addr = (size_t)m * N + cg * 4;
                if (OUT_MODE == 3) *(float4*)&Yf[addr] = v;
                *(ushort4*)&O1[addr] = hi;
                *(ushort4*)&O2[addr] = lo;
            }
        }
    }
}

// ---------------------------------------------------------------------------
// e = sym MFMA (r7 proven: f16 e, upper-tri, coalesced dual write, XCD swz)
// ---------------------------------------------------------------------------
__global__ __launch_bounds__(256) void k_esym_mfma(const ushortT* __restrict__ wHi,
                                                   const ushortT* __restrict__ wLo,
                                                   const ushortT* __restrict__ hHi,
                                                   const ushortT* __restrict__ hLo,
                                                   ushortT* __restrict__ e) {
    __shared__ ushortT smem[20480];
    ushortT* sWjHi = smem;
    ushortT* sWjLo = smem + 2560;
    ushortT* sHjHi = smem + 5120;
    ushortT* sHjLo = smem + 7680;
    ushortT* sWkHi = smem + 10240;
    ushortT* sWkLo = smem + 12800;
    ushortT* sHkHi = smem + 15360;
    ushortT* sHkLo = smem + 17920;

    const int wgid = blockIdx.x;
    const int flat = (wgid & 7) * 272 + (wgid >> 3);
    const int bh = flat / 136;
    int idx = flat % 136, tj = 0;
    while (idx >= 16 - tj) { idx -= 16 - tj; tj++; }
    const int tk = tj + idx;
    const int j0 = tj * 64, k0 = tk * 64;
    const int t = threadIdx.x;
    const int wave = t >> 6, lane = t & 63;
    const int wr = wave >> 1, wc = wave & 1;
    const int lrow = lane & 15, lg = lane >> 4;

    f32x4 acc[2][2];
#pragma unroll
    for (int m = 0; m < 2; m++)
#pragma unroll
        for (int n = 0; n < 2; n++) {
            acc[m][n][0] = 0.f; acc[m][n][1] = 0.f;
            acc[m][n][2] = 0.f; acc[m][n][3] = 0.f;
        }

    const size_t bhbase = (size_t)bh * NN * DD;

    for (int d0 = 0; d0 < DD; d0 += 32) {
        __syncthreads();
        {
            const int row = t >> 2, cu = (t & 3) * 8;
#define STAGE1(SRC, DST, BASE)                                                    \
            *(uint4*)&DST[row * 40 + cu] =                                        \
                *(const uint4*)&SRC[bhbase + (size_t)(BASE + row) * DD + d0 + cu];
            STAGE1(wHi, sWjHi, j0) STAGE1(wLo, sWjLo, j0)
            STAGE1(hHi, sHjHi, j0) STAGE1(hLo, sHjLo, j0)
            STAGE1(wHi, sWkHi, k0) STAGE1(wLo, sWkLo, k0)
            STAGE1(hHi, sHkHi, k0) STAGE1(hLo, sHkLo, k0)
#undef STAGE1
        }
        __syncthreads();

        bf16x8 a0[2], a1[2], b0[2], b1[2];
#pragma unroll
        for (int m = 0; m < 2; m++) {
            const int off = (wr * 32 + m * 16 + lrow) * 40 + lg * 8;
            a0[m] = *(const bf16x8*)&sWjHi[off];
            a1[m] = *(const bf16x8*)&sWjLo[off];
        }
#pragma unroll
        for (int n = 0; n < 2; n++) {
            const int off = (wc * 32 + n * 16 + lrow) * 40 + lg * 8;
            b0[n] = *(const bf16x8*)&sHkHi[off];
            b1[n] = *(const bf16x8*)&sHkLo[off];
        }
#pragma unroll
        for (int m = 0; m < 2; m++)
#pragma unroll
            for (int n = 0; n < 2; n++) {
                acc[m][n] = __builtin_amdgcn_mfma_f32_16x16x32_bf16(a0[m], b0[n], acc[m][n], 0, 0, 0);
                acc[m][n] = __builtin_amdgcn_mfma_f32_16x16x32_bf16(a0[m], b1[n], acc[m][n], 0, 0, 0);
                acc[m][n] = __builtin_amdgcn_mfma_f32_16x16x32_bf16(a1[m], b0[n], acc[m][n], 0, 0, 0);
            }
#pragma unroll
        for (int m = 0; m < 2; m++) {
            const int off = (wr * 32 + m * 16 + lrow) * 40 + lg * 8;
            a0[m] = *(const bf16x8*)&sHjHi[off];
            a1[m] = *(const bf16x8*)&sHjLo[off];
        }
#pragma unroll
        for (int n = 0; n < 2; n++) {
            const int off = (wc * 32 + n * 16 + lrow) * 40 + lg * 8;
            b0[n] = *(const bf16x8*)&sWkHi[off];
            b1[n] = *(const bf16x8*)&sWkLo[off];
        }
#pragma unroll
        for (int m = 0; m < 2; m++)
#pragma unroll
            for (int n = 0; n < 2; n++) {
                acc[m][n] = __builtin_amdgcn_mfma_f32_16x16x32_bf16(a0[m], b0[n], acc[m][n], 0, 0, 0);
                acc[m][n] = __builtin_amdgcn_mfma_f32_16x16x32_bf16(a0[m], b1[n], acc[m][n], 0, 0, 0);
                acc[m][n] = __builtin_amdgcn_mfma_f32_16x16x32_bf16(a1[m], b0[n], acc[m][n], 0, 0, 0);
            }
    }

    __syncthreads();
    ushortT* tileN = smem;
    ushortT* tileT = smem + 4608;
#pragma unroll
    for (int m = 0; m < 2; m++)
#pragma unroll
        for (int n = 0; n < 2; n++) {
            const int jlb = wr * 32 + m * 16 + lg * 4;
            const int kl  = wc * 32 + n * 16 + lrow;
            ushort4 tv;
            tv.x = f2h(acc[m][n][0]); tv.y = f2h(acc[m][n][1]);
            tv.z = f2h(acc[m][n][2]); tv.w = f2h(acc[m][n][3]);
            tileN[(jlb + 0) * 72 + kl] = tv.x;
            tileN[(jlb + 1) * 72 + kl] = tv.y;
            tileN[(jlb + 2) * 72 + kl] = tv.z;
            tileN[(jlb + 3) * 72 + kl] = tv.w;
            *(ushort4*)&tileT[kl * 72 + jlb] = tv;
        }
    __syncthreads();
#pragma unroll
    for (int it = 0; it < 4; it++) {
        const int i2 = t + it * 256;
        const int row = i2 >> 4, ch = (i2 & 15) * 4;
        *(uint2*)&e[((size_t)bh * NN + j0 + row) * NN + k0 + ch] =
            *(const uint2*)&tileN[row * 72 + ch];
        if (tj != tk)
            *(uint2*)&e[((size_t)bh * NN + k0 + row) * NN + j0 + ch] =
                *(const uint2*)&tileT[row * 72 + ch];
    }
}

// ---------------------------------------------------------------------------
__global__ __launch_bounds__(256) void k_buildT(const float* __restrict__ adj,
                                                u64* __restrict__ bits) {
    const int gid = blockIdx.x * 256 + threadIdx.x;
    const int k  = gid & 1023;
    const int tw = (gid >> 10) & 15;
    const int b  = gid >> 14;
    const float* ac = adj + ((size_t)b << 20) + k;
    u64 w = 0;
#pragma unroll 8
    for (int jj = 0; jj < 64; jj++) {
        if (ac[(size_t)(tw * 64 + jj) << 10] != 0.f) w |= 1ull << jj;
    }
    bits[((size_t)((b << 10) | k)) * 16 + tw] = w;
}

__global__ __launch_bounds__(256) void k_cnt(const u64* __restrict__ bits,
                                             int* __restrict__ ccnt) {
    const int gid = blockIdx.x * 256 + threadIdx.x;
    const u64* wb = bits + (size_t)gid * 16;
    int c = 0;
#pragma unroll
    for (int tw = 0; tw < 16; tw++) c += __popcll(wb[tw]);
    ccnt[gid] = c;
}

// ---------------------------------------------------------------------------
__global__ __launch_bounds__(256) void k_smA(const ushortT* __restrict__ e,
                                             const u64* __restrict__ bits,
                                             float* __restrict__ pm,
                                             float* __restrict__ ps) {
    const int gid = blockIdx.x * 256 + threadIdx.x;
    const int kg = gid & 255;
    const int jc = (gid >> 8) & 63;
    const int bh = gid >> 14;
    const int b  = bh >> 1;
    const int k4 = kg * 4;
    const int tw = jc >> 2;
    const int bo = (jc & 3) * 16;
    u64 w[4];
#pragma unroll
    for (int i = 0; i < 4; i++)
        w[i] = bits[((size_t)((b << 10) | (k4 + i))) * 16 + tw];
    const ushortT* ec = e + ((size_t)bh << 20) + (size_t)(jc * 16) * NN + k4;
    float m[4] = {0.f, 0.f, 0.f, 0.f};
    float s[4] = {0.f, 0.f, 0.f, 0.f};
#pragma unroll
    for (int r = 0; r < 16; r++) {
        const ushort4 ev = *(const ushort4*)&ec[(size_t)r * NN];
        const float evs[4] = {h2f(ev.x), h2f(ev.y), h2f(ev.z), h2f(ev.w)};
#pragma unroll
        for (int i = 0; i < 4; i++) {
            const bool on = (w[i] >> (bo + r)) & 1;
            const float v = on ? evs[i] : 0.f;
            const float mn = fmaxf(m[i], v);
            s[i] = s[i] * __expf(m[i] - mn) + (on ? __expf(v - mn) : 0.f);
            m[i] = mn;
        }
    }
    const size_t o = (((size_t)bh * 64 + jc) << 10) + k4;
    *(float4*)&pm[o] = make_float4(m[0], m[1], m[2], m[3]);
    *(float4*)&ps[o] = make_float4(s[0], s[1], s[2], s[3]);
}

__global__ __launch_bounds__(256) void k_smB(const float* __restrict__ pm,
                                             const float* __restrict__ ps,
                                             const int* __restrict__ ccnt,
                                             float* __restrict__ smax,
                                             float* __restrict__ sdinv) {
    __shared__ float lm[4][64], ls[4][64];
    const int t = threadIdx.x, q = t >> 6, lane = t & 63;
    const int colg = blockIdx.x * 64 + lane;
    const int bh = colg >> 10, k = colg & 1023;
    const int b  = bh >> 1;
    float M = 0.f, S = 0.f;
#pragma unroll 4
    for (int i = 0; i < 16; i++) {
        const int jc = q * 16 + i;
        const size_t o = (((size_t)bh * 64 + jc) << 10) + k;
        const float pmv = pm[o], psv = ps[o];
        const float mn = fmaxf(M, pmv);
        S = S * __expf(M - mn) + psv * __expf(pmv - mn);
        M = mn;
    }
    lm[q][lane] = M; ls[q][lane] = S;
    __syncthreads();
    if (q == 0) {
#pragma unroll
        for (int qq = 1; qq < 4; qq++) {
            const float pmv = lm[qq][lane], psv = ls[qq][lane];
            const float mn = fmaxf(M, pmv);
            S = S * __expf(M - mn) + psv * __expf(pmv - mn);
            M = mn;
        }
        S += (float)(NN - ccnt[(b << 10) + k]) * __expf(-M);
        smax[colg] = M;
        sdinv[colg] = 1.f / S;
    }
}

__global__ __launch_bounds__(256) void k_smC(const ushortT* __restrict__ e,
                                             const u64* __restrict__ bits,
                                             const float* __restrict__ smax,
                                             const float* __restrict__ sdinv,
                                             ushortT* __restrict__ att) {
    const int gid = blockIdx.x * 256 + threadIdx.x;
    const int kg = gid & 255;
    const int jc = (gid >> 8) & 63;
    const int bh = gid >> 14;
    const int b  = bh >> 1;
    const int k4 = kg * 4;
    const int tw = jc >> 2;
    const int bo = (jc & 3) * 16;
    u64 w[4];
#pragma unroll
    for (int i = 0; i < 4; i++)
        w[i] = bits[((size_t)((b << 10) | (k4 + i))) * 16 + tw];
    const float4 m4 = *(const float4*)&smax[(bh << 10) + k4];
    const float4 d4 = *(const float4*)&sdinv[(bh << 10) + k4];
    const float ms[4] = {m4.x, m4.y, m4.z, m4.w};
    const float ds[4] = {d4.x, d4.y, d4.z, d4.w};
    const ushortT* ec = e + ((size_t)bh << 20) + (size_t)(jc * 16) * NN + k4;
    ushortT* ac = att + ((size_t)bh << 20) + (size_t)(jc * 16) * NN + k4;
#pragma unroll
    for (int r = 0; r < 16; r++) {
        const ushort4 ev = *(const ushort4*)&ec[(size_t)r * NN];
        const float evs[4] = {h2f(ev.x), h2f(ev.y), h2f(ev.z), h2f(ev.w)};
        ushort4 o;
        ushortT os[4];
#pragma unroll
        for (int i = 0; i < 4; i++) {
            const bool on = (w[i] >> (bo + r)) & 1;
            os[i] = f2h(on ? __expf(evs[i] - ms[i]) * ds[i] : 0.f);
        }
        o.x = os[0]; o.y = os[1]; o.z = os[2]; o.w = os[3];
        *(ushort4*)&ac[(size_t)r * NN] = o;
    }
}

// ---------------------------------------------------------------------------
__global__ __launch_bounds__(256) void k_trT(const float* __restrict__ h,
                                             ushortT* __restrict__ hT) {
    __shared__ float tile[64][65];
    const int bh = blockIdx.z;
    const int n0 = blockIdx.x * 64, d0 = blockIdx.y * 64;
    const int t = threadIdx.x;
#pragma unroll
    for (int q = 0; q < 16; q++) {
        const int idx = t + q * 256;
        const int row = idx >> 6, col = idx & 63;
        tile[row][col] = h[(size_t)bh * 131072 + (size_t)(n0 + row) * DD + d0 + col];
    }
    __syncthreads();
#pragma unroll
    for (int q = 0; q < 16; q++) {
        const int idx = t + q * 256;
        const int row = idx >> 6, col = idx & 63;
        hT[(size_t)bh * 131072 + (size_t)(d0 + row) * NN + n0 + col] = f2h(tile[col][row]);
    }
}

// zT f16 [bh][d][n] -> relu + bf16 hi/lo split [bh][n][d]  (feeds Wo MFMA)
__global__ __launch_bounds__(256) void k_fin(const ushortT* __restrict__ zT,
                                             ushortT* __restrict__ zHi,
                                             ushortT* __restrict__ zLo) {
    __shared__ float tile[64][65];
    const int bh = blockIdx.z;
    const int n0 = blockIdx.x * 64, d0 = blockIdx.y * 64;
    const int t = threadIdx.x;
#pragma unroll
    for (int q = 0; q < 16; q++) {
        const int idx = t + q * 256;
        const int row = idx >> 6, col = idx & 63;
        tile[row][col] = h2f(zT[(size_t)bh * 131072 + (size_t)(d0 + row) * NN + n0 + col]);
    }
    __syncthreads();
#pragma unroll
    for (int q = 0; q < 16; q++) {
        const int idx = t + q * 256;
        const int row = idx >> 6, col = idx & 63;
        const float v = fmaxf(tile[col][row], 0.f);
        const ushortT hi = f2bf(v);
        const size_t addr = (size_t)bh * 131072 + (size_t)(n0 + row) * DD + d0 + col;
        zHi[addr] = hi;
        zLo[addr] = f2bf(v - bf2f(hi));
    }
}

// ---------------------------------------------------------------------------
// Dense f16 MFMA hop, 8 waves / 512 threads, j-chunk 128, XCD swizzle.
// out = relu(att @ zinT) [+ fused beta-mix], transposed write.
// ---------------------------------------------------------------------------
template<bool FUSED>
__global__ __launch_bounds__(512) void k_hop(const ushortT* __restrict__ att,
                                             const ushortT* __restrict__ zin,
                                             const ushortT* __restrict__ hT,
                                             const float* __restrict__ beta,
                                             ushortT* __restrict__ zout) {
    __shared__ ushortT sA[64 * 136];
    __shared__ ushortT sB[128 * 136];
    const int bid = blockIdx.x;                 // 256 = 8 XCD x 32
    const int flat = (bid & 7) * 32 + (bid >> 3);
    const int bh = flat >> 4;
    const int i0 = (flat & 15) * 64;
    const int t = threadIdx.x, wave = t >> 6, lane = t & 63;
    const int wr = wave >> 2, wc = wave & 3;
    const int lrow = lane & 15, lg = lane >> 4;
    const ushortT* attb = att + ((size_t)bh << 20);
    const ushortT* zb   = zin + (size_t)bh * 131072;

    f32x4 acc[2][2];
#pragma unroll
    for (int m = 0; m < 2; m++)
#pragma unroll
        for (int n = 0; n < 2; n++) {
            acc[m][n][0]=0.f; acc[m][n][1]=0.f; acc[m][n][2]=0.f; acc[m][n][3]=0.f;
        }

    for (int j0 = 0; j0 < NN; j0 += 128) {
        __syncthreads();
#pragma unroll
        for (int q = 0; q < 2; q++) {           // sA: 64x128 = 1024 uint4
            const int u = t + q * 512;
            const int row = u >> 4, c8 = (u & 15) * 8;
            *(uint4*)&sA[row * 136 + c8] =
                *(const uint4*)&attb[(size_t)(i0 + row) * NN + j0 + c8];
        }
#pragma unroll
        for (int q = 0; q < 4; q++) {           // sB: 128x128 = 2048 uint4
            const int u = t + q * 512;
            const int row = u >> 4, c8 = (u & 15) * 8;
            *(uint4*)&sB[row * 136 + c8] =
                *(const uint4*)&zb[(size_t)row * NN + j0 + c8];
        }
        __syncthreads();
#pragma unroll
        for (int ks = 0; ks < 4; ks++) {
            f16x8 a[2], b[2];
#pragma unroll
            for (int m = 0; m < 2; m++)
                a[m] = *(const f16x8*)&sA[(wr * 32 + m * 16 + lrow) * 136 + ks * 32 + lg * 8];
#pragma unroll
            for (int n = 0; n < 2; n++)
                b[n] = *(const f16x8*)&sB[(wc * 32 + n * 16 + lrow) * 136 + ks * 32 + lg * 8];
#pragma unroll
            for (int m = 0; m < 2; m++)
#pragma unroll
                for (int n = 0; n < 2; n++)
                    acc[m][n] = __builtin_amdgcn_mfma_f32_16x16x32_f16(a[m], b[n], acc[m][n], 0, 0, 0);
        }
    }

    const float* betab = beta + ((size_t)bh << 10);
    const ushortT* hTb = hT + (size_t)bh * 131072;
    ushortT* zo = zout + (size_t)bh * 131072;
#pragma unroll
    for (int m = 0; m < 2; m++)
#pragma unroll
        for (int n = 0; n < 2; n++) {
            const int d = wc * 32 + n * 16 + lrow;
            const int i = i0 + wr * 32 + m * 16 + lg * 4;
            ushort4 o;
            float vq[4];
            if (FUSED) {
                const float4 bev = *(const float4*)&betab[i];
                const ushort4 hv = *(const ushort4*)&hTb[(size_t)d * NN + i];
                vq[0] = bev.x * h2f(hv.x) + (1.f - bev.x) * fmaxf(acc[m][n][0], 0.f);
                vq[1] = bev.y * h2f(hv.y) + (1.f - bev.y) * fmaxf(acc[m][n][1], 0.f);
                vq[2] = bev.z * h2f(hv.z) + (1.f - bev.z) * fmaxf(acc[m][n][2], 0.f);
                vq[3] = bev.w * h2f(hv.w) + (1.f - bev.w) * fmaxf(acc[m][n][3], 0.f);
            } else {
                vq[0] = fmaxf(acc[m][n][0], 0.f); vq[1] = fmaxf(acc[m][n][1], 0.f);
                vq[2] = fmaxf(acc[m][n][2], 0.f); vq[3] = fmaxf(acc[m][n][3], 0.f);
            }
            o.x = f2h(vq[0]); o.y = f2h(vq[1]); o.z = f2h(vq[2]); o.w = f2h(vq[3]);
            *(ushort4*)&zo[(size_t)d * NN + i] = o;
        }
}

// ---------------------------------------------------------------------------
__global__ __launch_bounds__(256) void k_betaA(const ushortT* __restrict__ hT,
                                               const ushortT* __restrict__ azT,
                                               const float* __restrict__ Wbw,
                                               float* __restrict__ pb) {
    const int gid = blockIdx.x * 256 + threadIdx.x;
    const int n  = gid & 1023;
    const int bh = (gid >> 10) & 15;
    const int dc = gid >> 14;
    const size_t base = (size_t)bh * 131072 + ((size_t)(dc * 32) << 10) + n;
    const ushortT* hp = hT  + base;
    const ushortT* ap = azT + base;
    float s = 0.f;
#pragma unroll 8
    for (int d = 0; d < 32; d++)
        s += h2f(hp[(size_t)d << 10]) * Wbw[dc * 32 + d]
           + h2f(ap[(size_t)d << 10]) * Wbw[DD + dc * 32 + d];
    pb[gid] = s;
}

__global__ __launch_bounds__(256) void k_betaB(const float* __restrict__ pb,
                                               const float* __restrict__ Wbb,
                                               float* __restrict__ beta) {
    const int gid = blockIdx.x * 256 + threadIdx.x;
    const float s = pb[gid] + pb[gid + 16384] + pb[gid + 32768] + pb[gid + 49152];
    beta[gid] = 1.f / (1.f + expf(-(s + Wbb[0])));
}

__global__ __launch_bounds__(256) void k_zupT(const ushortT* __restrict__ hT,
                                              const ushortT* __restrict__ azT,
                                              const float* __restrict__ beta,
                                              ushortT* __restrict__ zT) {
    const int gid = blockIdx.x * 256 + threadIdx.x;
    const size_t base = (size_t)gid * 8;
    const int n0 = (int)(base & 1023);
    const int bh = (int)(base >> 17);
    ushortT hu[8], au[8], ou[8];
    *(uint4*)hu = *(const uint4*)&hT[base];
    *(uint4*)au = *(const uint4*)&azT[base];
    const float4 b0 = *(const float4*)&beta[(bh << 10) + n0];
    const float4 b1 = *(const float4*)&beta[(bh << 10) + n0 + 4];
    const float be[8] = {b0.x, b0.y, b0.z, b0.w, b1.x, b1.y, b1.z, b1.w};
#pragma unroll
    for (int i = 0; i < 8; i++)
        ou[i] = f2h(be[i] * h2f(hu[i]) + (1.f - be[i]) * h2f(au[i]));
    *(uint4*)&zT[base] = *(uint4*)ou;
}

// c = c2 - c1 fp32 + bf16 hi/lo split (feeds next layer's Wh MFMA)
__global__ __launch_bounds__(256) void k_sub(const float* __restrict__ c2,
                                             const float* __restrict__ c1,
                                             float* __restrict__ c,
                                             ushortT* __restrict__ cHi,
                                             ushortT* __restrict__ cLo) {
    const int g = blockIdx.x * 256 + threadIdx.x;
    const float4 a = ((const float4*)c2)[g];
    const float4 b = ((const float4*)c1)[g];
    const float4 v = make_float4(a.x - b.x, a.y - b.y, a.z - b.z, a.w - b.w);
    ((float4*)c)[g] = v;
    ushort4 hi, lo;
    hi.x = f2bf(v.x); lo.x = f2bf(v.x - bf2f(hi.x));
    hi.y = f2bf(v.y); lo.y = f2bf(v.y - bf2f(hi.y));
    hi.z = f2bf(v.z); lo.z = f2bf(v.z - bf2f(hi.z));
    hi.w = f2bf(v.w); lo.w = f2bf(v.w - bf2f(hi.w));
    ((ushort4*)cHi)[g] = hi;
    ((ushort4*)cLo)[g] = lo;
}

// parallel masked mean pool: partials then combine
__global__ __launch_bounds__(128) void k_poolA(const float* __restrict__ c,
                                               const float* __restrict__ valid,
                                               float* __restrict__ pp,
                                               float* __restrict__ pv) {
    const int bc = blockIdx.x;                    // 8*16
    const int b = bc >> 4, ch = bc & 15;
    const int d = threadIdx.x;
    const float* cb = c + ((size_t)b << 17) + (size_t)(ch * 64) * DD;
    const float* vb = valid + (b << 10) + ch * 64;
    float s = 0.f, sv = 0.f;
#pragma unroll 8
    for (int i = 0; i < 64; i++) { const float v = vb[i]; s += cb[(size_t)i * DD + d] * v; sv += v; }
    pp[bc * 128 + d] = s;
    if (d == 0) pv[bc] = sv;
}

__global__ __launch_bounds__(256) void k_poolB(const float* __restrict__ pp,
                                               const float* __restrict__ pv,
                                               float* __restrict__ pooled) {
    const int gid = blockIdx.x * 256 + threadIdx.x;   // 1024
    const int b = gid >> 7, d = gid & 127;
    float s = 0.f, sv = 0.f;
#pragma unroll
    for (int ch = 0; ch < 16; ch++) {
        s  += pp[(b * 16 + ch) * 128 + d];
        sv += pv[b * 16 + ch];
    }
    pooled[b * 128 + d] = s / sv;
}

template<int K, int NOUT, bool RELU>
__global__ void k_fc(const float* __restrict__ X, const float* __restrict__ W,
                     const float* __restrict__ bias, float* __restrict__ Y) {
    const int gid = blockIdx.x * blockDim.x + threadIdx.x;
    if (gid >= BB * NOUT) return;
    const int b = gid / NOUT, o = gid % NOUT;
    float s = bias[o];
    for (int i = 0; i < K; i++) s += X[(size_t)b * K + i] * W[(size_t)i * NOUT + o];
    Y[gid] = RELU ? fmaxf(s, 0.f) : s;
}

__global__ void k_fc2(const float* __restrict__ X, const float* __restrict__ W,
                      const float* __restrict__ bias, float* __restrict__ out) {
    const int b = threadIdx.x >> 6, lane = threadIdx.x & 63;
    float s = 0.f;
    for (int i = lane; i < DFCN; i += 64) s += X[(size_t)b * DFCN + i] * W[i];
#pragma unroll
    for (int off = 32; off > 0; off >>= 1) s += __shfl_down(s, off);
    if (lane == 0) out[b] = 1.f / (1.f + expf(-(s + bias[0])));
}

// ---------------------------------------------------------------------------
extern "C" void kernel_launch(void* const* d_in, const int* in_sizes, int n_in,
                              void* d_out, int out_size, void* d_ws, size_t ws_size,
                              hipStream_t stream) {
    const float* x        = (const float*)d_in[0];
    const float* adj1     = (const float*)d_in[1];
    const float* adj2     = (const float*)d_in[2];
    const float* valid    = (const float*)d_in[3];
    const float* embede_w = (const float*)d_in[4];
    const float* Wh       = (const float*)d_in[5];
    const float* We       = (const float*)d_in[6];
    const float* Wbw      = (const float*)d_in[7];
    const float* Wbb      = (const float*)d_in[8];
    const float* Wo       = (const float*)d_in[9];
    const float* fc0_w    = (const float*)d_in[10];
    const float* fc0_b    = (const float*)d_in[11];
    const float* fc1_w    = (const float*)d_in[12];
    const float* fc1_b    = (const float*)d_in[13];
    const float* fc2_w    = (const float*)d_in[14];
    const float* fc2_b    = (const float*)d_in[15];

    // ---- workspace carve: ~143 MB ----
    float* ws = (float*)d_ws;
    float* c      = ws;                          // 1,048,576 f
    float* h      = c      + (size_t)1048576;    // 2,097,152 f
    float* c1     = h      + (size_t)2097152;    // 1,048,576 f
    float* c2     = c1     + (size_t)1048576;    // 1,048,576 f
    float* beta   = c2     + (size_t)1048576;    // 16,384 f
    float* pm     = beta   + (size_t)16384;      // 1,048,576 f
    float* ps     = pm     + (size_t)1048576;    // 1,048,576 f
    float* smax   = ps     + (size_t)1048576;    // 16,384 f
    float* sdinv  = smax   + (size_t)16384;      // 16,384 f
    float* pb     = sdinv  + (size_t)16384;      // 65,536 f
    float* pp     = pb     + (size_t)65536;      // 16,384 f
    float* pv     = pp     + (size_t)16384;      // 128 f
    float* pooled = pv     + (size_t)128;        // 1,024 f
    float* f0     = pooled + (size_t)1024;       // 4,096 f
    float* f1     = f0     + (size_t)4096;       // 4,096 f
    ushortT* hHi  = (ushortT*)(f1 + 4096);       // 2,097,152 us each
    ushortT* hLo  = hHi + (size_t)2097152;
    ushortT* wHi  = hLo + (size_t)2097152;
    ushortT* wLo  = wHi + (size_t)2097152;
    ushortT* hT   = wLo + (size_t)2097152;
    ushortT* zTa  = hT  + (size_t)2097152;
    ushortT* zTb  = zTa + (size_t)2097152;
    ushortT* cHi  = zTb + (size_t)2097152;       // 1,048,576 us each
    ushortT* cLo  = cHi + (size_t)1048576;
    ushortT* zHi  = cLo + (size_t)1048576;       // 2,097,152 us each
    ushortT* zLo  = zHi + (size_t)2097152;
    ushortT* att  = zLo + (size_t)2097152;       // 16,777,216 us
    ushortT* e    = att + (size_t)16777216;      // 16,777,216 us
    ushortT* WhTh = e   + (size_t)16777216;      // 131,072 us each
    ushortT* WhTl = WhTh + (size_t)131072;
    ushortT* WeTh = WhTl + (size_t)131072;       // 65,536 each
    ushortT* WeTl = WeTh + (size_t)65536;
    ushortT* WoTh = WeTl + (size_t)65536;        // 131,072 each
    ushortT* WoTl = WoTh + (size_t)131072;
    ushortT* EmTh = WoTl + (size_t)131072;       // 16,384 each
    ushortT* EmTl = EmTh + (size_t)16384;
    u64* bits1    = (u64*)(EmTl + (size_t)16384);
    u64* bits2    = bits1 + (size_t)131072;
    int* ccnt1    = (int*)(bits2 + (size_t)131072);
    int* ccnt2    = ccnt1 + 8192;

    // ---- one-time per launch: masks + weight splits ----
    k_buildT<<<512, 256, 0, stream>>>(adj1, bits1);
    k_buildT<<<512, 256, 0, stream>>>(adj2, bits2);
    k_cnt<<<32, 256, 0, stream>>>(bits1, ccnt1);
    k_cnt<<<32, 256, 0, stream>>>(bits2, ccnt2);
    k_splitWT<128,256><<<dim3(8,4,4), 256, 0, stream>>>(Wh, WhTh, WhTl);
    k_splitWT<128,128><<<dim3(4,4,4), 256, 0, stream>>>(We, WeTh, WeTl);
    k_splitWT<256,128><<<dim3(4,8,4), 256, 0, stream>>>(Wo, WoTh, WoTl);
    k_splitWT<128,128><<<dim3(4,4,1), 256, 0, stream>>>(embede_w, EmTh, EmTl);

    // c = x @ embede_w (fp32-in split-on-fly, fp32 + split out)
    k_mgemm<128,128,32,false,2,3><<<256, 256, 0, stream>>>(
        nullptr, nullptr, x, EmTh, EmTl, c, cHi, cLo);

    for (int k = 0; k < LL; k++) {
        const int nhop = k + 1;
        // h = relu(c @ Wh[k]) -> scatter [bh][n][d] fp32 + splits
        k_mgemm<128,256,32,true,0,1><<<256, 256, 0, stream>>>(
            cHi, cLo, nullptr, WhTh + (size_t)k*32768, WhTl + (size_t)k*32768, h, hHi, hLo);
        // hW = h @ We[k] -> splits row-major
        k_mgemm<128,128,64,false,0,2><<<256, 256, 0, stream>>>(
            hHi, hLo, nullptr, WeTh + (size_t)k*16384, WeTl + (size_t)k*16384, nullptr, wHi, wLo);
        k_trT<<<dim3(16,2,16), 256, 0, stream>>>(h, hT);
        k_esym_mfma<<<2176, 256, 0, stream>>>(wHi, wLo, hHi, hLo, e);

        for (int br = 0; br < 2; br++) {
            const u64* bits = (br == 0) ? bits1 : bits2;
            const int* ccnt = (br == 0) ? ccnt1 : ccnt2;
            float*     cb   = (br == 0) ? c1    : c2;

            k_smA<<<1024, 256, 0, stream>>>(e, bits, pm, ps);
            k_smB<<<256, 256, 0, stream>>>(pm, ps, ccnt, smax, sdinv);
            k_smC<<<1024, 256, 0, stream>>>(e, bits, smax, sdinv, att);

            k_hop<false><<<256, 512, 0, stream>>>(att, hT, hT, beta, zTb);
            k_betaA<<<256, 256, 0, stream>>>(hT, zTb, Wbw + (size_t)k*256, pb);
            k_betaB<<<64, 256, 0, stream>>>(pb, Wbb + k, beta);
            k_zupT<<<1024, 256, 0, stream>>>(hT, zTb, beta, zTa);
            ushortT* zA = zTa; ushortT* zB = zTb;
            for (int tpp = 1; tpp < nhop; tpp++) {
                k_hop<true><<<256, 512, 0, stream>>>(att, zA, hT, beta, zB);
                ushortT* tmp = zA; zA = zB; zB = tmp;
            }
            // relu+split z -> zHi/zLo; cb = relu(z) @ Wo[k]
            k_fin<<<dim3(16,2,16), 256, 0, stream>>>(zA, zHi, zLo);
            k_mgemm<256,128,32,false,1,0><<<256, 256, 0, stream>>>(
                zHi, zLo, nullptr, WoTh + (size_t)k*32768, WoTl + (size_t)k*32768, cb, nullptr, nullptr);
        }
        k_sub<<<1024, 256, 0, stream>>>(c2, c1, c, cHi, cLo);
    }

    k_poolA<<<128, 128, 0, stream>>>(c, valid, pp, pv);
    k_poolB<<<4, 256, 0, stream>>>(pp, pv, pooled);
    k_fc<128, DFCN, true><<<16, 256, 0, stream>>>(pooled, fc0_w, fc0_b, f0);
    k_fc<DFCN, DFCN, true><<<16, 256, 0, stream>>>(f0, fc1_w, fc1_b, f1);
    k_fc2<<<1, 512, 0, stream>>>(f1, fc2_w, fc2_b, (float*)d_out);
}